// Round 3
// baseline (414.489 us; speedup 1.0000x reference)
//
#include <hip/hip_runtime.h>
#include <math.h>

#define S_LEN 2048
#define NH 16
#define DH 128
#define INNER 2048   // NH*DH
#define NROWS 4096   // B*S

typedef __attribute__((ext_vector_type(8))) short bf16x8;
typedef __attribute__((ext_vector_type(4))) float f32x4;

__device__ __forceinline__ short f2bf(float f) {
  union { float f; unsigned u; } v; v.f = f;
  unsigned r = (v.u + 0x7fffu + ((v.u >> 16) & 1u)) >> 16;
  return (short)(unsigned short)r;
}

// ---------------- fused prep: rope table + W transposes ----------------
// grid 1536: [0,512) rope table; [512,1280) Wq/Wk/Wv transpose; [1280,1536) Wo
__global__ void k_prep(const float* __restrict__ Wq, const float* __restrict__ Wk,
                       const float* __restrict__ Wv, const float* __restrict__ Wo,
                       float* __restrict__ rc, float* __restrict__ rs,
                       short* __restrict__ WT, short* __restrict__ WoT) {
  const int bx = blockIdx.x, tid = threadIdx.x;
  if (bx < 512) {
    int idx = bx * 256 + tid;           // S_LEN*64 entries
    int s = idx >> 6, i = idx & 63;
    double invf = pow(10000.0, -(double)i / 64.0);
    float ang = (float)((double)s * invf);
    float sv, cv; sincosf(ang, &sv, &cv);
    rc[idx] = cv; rs[idx] = sv;
    return;
  }
  __shared__ float tile[32][33];
  const float* src; short* dst; int R, C, c0, r0;
  if (bx < 1280) {
    int z = (bx - 512) >> 8, t = (bx - 512) & 255;
    src = (z == 0) ? Wq : ((z == 1) ? Wk : Wv);
    dst = WT + (size_t)z * INNER * 128; R = 128; C = INNER;
    c0 = (t & 63) * 32; r0 = (t >> 6) * 32;
  } else {
    int t = bx - 1280;
    src = Wo; dst = WoT; R = INNER; C = 128;
    c0 = (t & 3) * 32; r0 = (t >> 2) * 32;
  }
  int tx = tid & 31, ty = tid >> 5;     // 32 x 8
  #pragma unroll
  for (int dy = 0; dy < 32; dy += 8)
    tile[ty + dy][tx] = src[(size_t)(r0 + ty + dy) * C + c0 + tx];
  __syncthreads();
  #pragma unroll
  for (int dy = 0; dy < 32; dy += 8)
    dst[(size_t)(c0 + ty + dy) * R + r0 + tx] = f2bf(tile[tx][ty + dy]);
}

// ---------------- fused QKV projection + RoPE ----------------
// grid (32 n-tiles, 32 m-tiles), block 256. X staged once (fp32->bf16 in
// staging), z-loop over the three weight mats. Q,K [bh][s][d]; V [bh][d][s].
__global__ __launch_bounds__(256) void k_qkv(
    const float* __restrict__ X, const short* __restrict__ WT,
    const float* __restrict__ rc, const float* __restrict__ rs,
    short* __restrict__ Qg, short* __restrict__ Kg, short* __restrict__ Vg) {
  __shared__ __attribute__((aligned(16))) short As[128 * 136];
  __shared__ __attribute__((aligned(16))) short Bs[64 * 136];
  const int tid = threadIdx.x;
  const int n0 = blockIdx.x * 64, m0 = blockIdx.y * 128;
  for (int c = tid; c < 128 * 32; c += 256) {
    int row = c >> 5, cj = c & 31;
    float4 xv = *(const float4*)&X[(size_t)(m0 + row) * 128 + cj * 4];
    short4 o; o.x = f2bf(xv.x); o.y = f2bf(xv.y); o.z = f2bf(xv.z); o.w = f2bf(xv.w);
    *(short4*)&As[row * 136 + cj * 4] = o;
  }
  const int wid = tid >> 6, lane = tid & 63;
  const int l16 = lane & 15, quad = lane >> 4;
  const int wm = (wid & 1) * 64, wn = (wid >> 1) * 32;
  const float qscale = 0.08838834764831845f;   // 1/sqrt(128) folded into Q
  for (int z = 0; z < 3; ++z) {
    __syncthreads();   // As ready (z=0) / prior mfma LDS reads done (z>0)
    const short* Wp = WT + (size_t)z * INNER * 128;
    for (int c = tid; c < 64 * 16; c += 256) {
      int row = c >> 4, cj = c & 15;
      *(int4*)&Bs[row * 136 + cj * 8] = *(const int4*)&Wp[(size_t)(n0 + row) * 128 + cj * 8];
    }
    __syncthreads();
    f32x4 acc[4][2] = {};
    #pragma unroll
    for (int ks = 0; ks < 4; ++ks) {
      bf16x8 a[4], b[2];
      #pragma unroll
      for (int mt = 0; mt < 4; ++mt)
        a[mt] = *(const bf16x8*)&As[(wm + mt * 16 + l16) * 136 + ks * 32 + quad * 8];
      #pragma unroll
      for (int nt = 0; nt < 2; ++nt)
        b[nt] = *(const bf16x8*)&Bs[(wn + nt * 16 + l16) * 136 + ks * 32 + quad * 8];
      #pragma unroll
      for (int mt = 0; mt < 4; ++mt)
        #pragma unroll
        for (int nt = 0; nt < 2; ++nt)
          acc[mt][nt] = __builtin_amdgcn_mfma_f32_16x16x32_bf16(a[mt], b[nt], acc[mt][nt], 0, 0, 0);
    }
    if (z < 2) {
      #pragma unroll
      for (int mt = 0; mt < 4; ++mt)
        #pragma unroll
        for (int nt = 0; nt < 2; ++nt) {
          int gn = n0 + wn + nt * 16 + l16;
          int h = gn >> 7, d = gn & 127, i = d >> 1;
          #pragma unroll
          for (int r = 0; r < 4; ++r) {
            int gm = m0 + wm + mt * 16 + quad * 4 + r;
            int bb = gm >> 11, s = gm & 2047;
            float v = acc[mt][nt][r];
            float pv = __shfl_xor(v, 1);          // partner lane holds d^1
            float cv = rc[s * 64 + i], sv = rs[s * 64 + i];
            float res = (d & 1) ? (v * cv + pv * sv) : (v * cv - pv * sv);
            if (z == 0) res *= qscale;
            size_t off = (((size_t)(bb * NH + h)) * S_LEN + s) * DH + d;
            short bv = f2bf(res);
            if (z == 0) Qg[off] = bv; else Kg[off] = bv;
          }
        }
    } else {
      #pragma unroll
      for (int mt = 0; mt < 4; ++mt)
        #pragma unroll
        for (int nt = 0; nt < 2; ++nt) {
          int gn = n0 + wn + nt * 16 + l16;
          int h = gn >> 7, d = gn & 127;
          int gmb = m0 + wm + mt * 16 + quad * 4;
          int bb = gmb >> 11, s = gmb & 2047;
          short4 pk;
          pk.x = f2bf(acc[mt][nt][0]); pk.y = f2bf(acc[mt][nt][1]);
          pk.z = f2bf(acc[mt][nt][2]); pk.w = f2bf(acc[mt][nt][3]);
          *(short4*)&Vg[(((size_t)(bb * NH + h)) * DH + d) * S_LEN + s] = pk;
        }
    }
  }
}

// ---------------- flash attention: barrier-free, direct-fragment ----------------
// grid (32 bh, 16 pair), block 256 (4 waves, 16 q-rows each).
// XCD = (bh + 32*pair) % 8 = bh % 8 -> each XCD serves 4 bh; K+V working set
// 4 MB == L2. All fragments loaded global->VGPR in MFMA layout (no staging,
// ZERO __syncthreads). P^T transits a wave-private LDS slab (in-wave DS order).
__global__ __launch_bounds__(256, 2) void k_attn(
    const short* __restrict__ Qg, const short* __restrict__ Kg,
    const short* __restrict__ Vg, short* __restrict__ Og) {
  __shared__ __attribute__((aligned(16))) short Ps[4][16 * 72];
  const int bh = blockIdx.x, pr = blockIdx.y;
  const int bb = bh >> 4, h = bh & 15;
  const int tid = threadIdx.x, wid = tid >> 6, lane = tid & 63;
  const int l16 = lane & 15, quad = lane >> 4, wq = wid * 16;
  const short* Qp = Qg + (size_t)bh * S_LEN * DH;   // [s][d]
  const short* Kp = Kg + (size_t)bh * S_LEN * DH;   // [s][d]
  const short* Vp = Vg + (size_t)bh * S_LEN * DH;   // [d][s]
  short* psw = &Ps[wid][0];
  for (int ph = 0; ph < 2; ++ph) {
    const int qt = ph ? (31 - pr) : pr;
    const int q0 = qt * 64;
    // Q fragments: live in registers for the whole inner loop
    bf16x8 qf[4];
    #pragma unroll
    for (int ks = 0; ks < 4; ++ks)
      qf[ks] = *(const bf16x8*)&Qp[(size_t)(q0 + wq + l16) * DH + ks * 32 + quad * 8];
    // K fragments for tile 0
    bf16x8 kf[4][4];
    #pragma unroll
    for (int ks = 0; ks < 4; ++ks)
      #pragma unroll
      for (int nt = 0; nt < 4; ++nt)
        kf[ks][nt] = *(const bf16x8*)&Kp[(size_t)(nt * 16 + l16) * DH + ks * 32 + quad * 8];
    float m_i = -1e30f, l_i = 0.0f;
    f32x4 Oacc[8] = {};
    for (int j = 0; j <= qt; ++j) {
      // V fragments, first k-half (consumed by PV after softmax: latency hidden)
      bf16x8 vf0[8], vf1[8];
      #pragma unroll
      for (int nt = 0; nt < 8; ++nt)
        vf0[nt] = *(const bf16x8*)&Vp[(size_t)(nt * 16 + l16) * S_LEN + j * 64 + quad * 8];
      // S^T = K @ Q^T
      f32x4 Sc[4] = {};
      #pragma unroll
      for (int ks = 0; ks < 4; ++ks)
        #pragma unroll
        for (int nt = 0; nt < 4; ++nt)
          Sc[nt] = __builtin_amdgcn_mfma_f32_16x16x32_bf16(kf[ks][nt], qf[ks], Sc[nt], 0, 0, 0);
      // V second k-half in flight behind softmax
      #pragma unroll
      for (int nt = 0; nt < 8; ++nt)
        vf1[nt] = *(const bf16x8*)&Vp[(size_t)(nt * 16 + l16) * S_LEN + j * 64 + 32 + quad * 8];
      if (j == qt) {  // causal mask on diagonal: t_local > q_local
        #pragma unroll
        for (int nt = 0; nt < 4; ++nt)
          #pragma unroll
          for (int r = 0; r < 4; ++r)
            if (nt * 16 + quad * 4 + r > wq + l16) Sc[nt][r] = -1e30f;
      }
      // online softmax over t (16 in-lane + 2 cross-quad shfls)
      float mloc = -1e30f;
      #pragma unroll
      for (int nt = 0; nt < 4; ++nt)
        #pragma unroll
        for (int r = 0; r < 4; ++r) mloc = fmaxf(mloc, Sc[nt][r]);
      mloc = fmaxf(mloc, __shfl_xor(mloc, 16));
      mloc = fmaxf(mloc, __shfl_xor(mloc, 32));
      float mnew = fmaxf(m_i, mloc);
      float alpha = __expf(m_i - mnew);
      m_i = mnew;
      float rsum = 0.0f;
      #pragma unroll
      for (int nt = 0; nt < 4; ++nt)
        #pragma unroll
        for (int r = 0; r < 4; ++r) {
          float p = __expf(Sc[nt][r] - mnew);
          Sc[nt][r] = p;
          rsum += p;
        }
      rsum += __shfl_xor(rsum, 16);
      rsum += __shfl_xor(rsum, 32);
      l_i = l_i * alpha + rsum;
      #pragma unroll
      for (int nt = 0; nt < 8; ++nt)
        #pragma unroll
        for (int r = 0; r < 4; ++r) Oacc[nt][r] *= alpha;
      // prefetch K fragments for tile j+1 (QK done; regs free)
      if (j < qt) {
        #pragma unroll
        for (int ks = 0; ks < 4; ++ks)
          #pragma unroll
          for (int nt = 0; nt < 4; ++nt)
            kf[ks][nt] = *(const bf16x8*)&Kp[(size_t)((j + 1) * 64 + nt * 16 + l16) * DH +
                                             ks * 32 + quad * 8];
      }
      // P^T -> wave-private LDS (C-layout -> A/B-operand layout transform)
      #pragma unroll
      for (int nt = 0; nt < 4; ++nt) {
        short4 pk;
        pk.x = f2bf(Sc[nt][0]); pk.y = f2bf(Sc[nt][1]);
        pk.z = f2bf(Sc[nt][2]); pk.w = f2bf(Sc[nt][3]);
        *(short4*)&psw[l16 * 72 + nt * 16 + quad * 4] = pk;
      }
      // O^T += V^T @ P
      {
        bf16x8 bp0 = *(const bf16x8*)&psw[l16 * 72 + quad * 8];
        #pragma unroll
        for (int nt = 0; nt < 8; ++nt)
          Oacc[nt] = __builtin_amdgcn_mfma_f32_16x16x32_bf16(vf0[nt], bp0, Oacc[nt], 0, 0, 0);
        bf16x8 bp1 = *(const bf16x8*)&psw[l16 * 72 + 32 + quad * 8];
        #pragma unroll
        for (int nt = 0; nt < 8; ++nt)
          Oacc[nt] = __builtin_amdgcn_mfma_f32_16x16x32_bf16(vf1[nt], bp1, Oacc[nt], 0, 0, 0);
      }
    }
    float inv = 1.0f / l_i;
    size_t orow = ((size_t)(bb * S_LEN + q0 + wq + l16)) * INNER + h * DH;
    #pragma unroll
    for (int nt = 0; nt < 8; ++nt) {
      short4 ov;
      ov.x = f2bf(Oacc[nt][0] * inv); ov.y = f2bf(Oacc[nt][1] * inv);
      ov.z = f2bf(Oacc[nt][2] * inv); ov.w = f2bf(Oacc[nt][3] * inv);
      *(short4*)&Og[orow + nt * 16 + quad * 4] = ov;
    }
  }
}

// ---------------- output projection: Og[4096,2048] @ Wo[2048,128] ----------------
__global__ __launch_bounds__(256) void k_out(
    const short* __restrict__ Og, const short* __restrict__ WoT,
    float* __restrict__ out) {
  __shared__ __attribute__((aligned(16))) short As[128 * 72];
  __shared__ __attribute__((aligned(16))) short Bs[128 * 72];
  const int m0 = blockIdx.x * 128, kb0 = blockIdx.y * 512;
  const int tid = threadIdx.x, wid = tid >> 6, lane = tid & 63;
  const int l16 = lane & 15, quad = lane >> 4;
  const int wm = (wid & 1) * 64, wn = (wid >> 1) * 64;
  f32x4 acc[4][4] = {};
  for (int kc = 0; kc < 8; ++kc) {
    int k0 = kb0 + kc * 64;
    for (int c = tid; c < 128 * 8; c += 256) {
      int row = c >> 3, cj = c & 7;
      *(int4*)&As[row * 72 + cj * 8] =
          *(const int4*)&Og[(size_t)(m0 + row) * INNER + k0 + cj * 8];
    }
    for (int c = tid; c < 128 * 8; c += 256) {
      int row = c >> 3, cj = c & 7;
      *(int4*)&Bs[row * 72 + cj * 8] =
          *(const int4*)&WoT[(size_t)row * INNER + k0 + cj * 8];
    }
    __syncthreads();
    #pragma unroll
    for (int ks = 0; ks < 2; ++ks) {
      bf16x8 a[4], b[4];
      #pragma unroll
      for (int mt = 0; mt < 4; ++mt)
        a[mt] = *(const bf16x8*)&As[(wm + mt * 16 + l16) * 72 + ks * 32 + quad * 8];
      #pragma unroll
      for (int nt = 0; nt < 4; ++nt)
        b[nt] = *(const bf16x8*)&Bs[(wn + nt * 16 + l16) * 72 + ks * 32 + quad * 8];
      #pragma unroll
      for (int mt = 0; mt < 4; ++mt)
        #pragma unroll
        for (int nt = 0; nt < 4; ++nt)
          acc[mt][nt] = __builtin_amdgcn_mfma_f32_16x16x32_bf16(a[mt], b[nt], acc[mt][nt], 0, 0, 0);
    }
    __syncthreads();
  }
  #pragma unroll
  for (int mt = 0; mt < 4; ++mt)
    #pragma unroll
    for (int nt = 0; nt < 4; ++nt)
      #pragma unroll
      for (int r = 0; r < 4; ++r) {
        int gm = m0 + wm + mt * 16 + quad * 4 + r;
        int gn = wn + nt * 16 + l16;
        atomicAdd(&out[(size_t)gm * 128 + gn], acc[mt][nt][r]);
      }
}

// ---------------- launch ----------------
extern "C" void kernel_launch(void* const* d_in, const int* in_sizes, int n_in,
                              void* d_out, int out_size, void* d_ws, size_t ws_size,
                              hipStream_t stream) {
  const float* q  = (const float*)d_in[0];
  const float* Wq = (const float*)d_in[1];
  const float* Wk = (const float*)d_in[2];
  const float* Wv = (const float*)d_in[3];
  const float* Wo = (const float*)d_in[4];
  float* out = (float*)d_out;
  char* ws = (char*)d_ws;
  const size_t MB = 1024 * 1024;
  float* rc  = (float*)(ws + 0);                   // 512 KB
  float* rs  = (float*)(ws + 512 * 1024);          // 512 KB
  short* WT  = (short*)(ws + 1 * MB);              // 1.5 MB (Wq,Wk,Wv [n][k] bf16)
  short* WoT = (short*)(ws + 2 * MB + 512 * 1024); // 512 KB
  short* Qg  = (short*)(ws + 4 * MB);              // 16 MB  [bh][s][d]
  short* Kg  = (short*)(ws + 20 * MB);             // 16 MB  [bh][s][d]
  short* Vg  = (short*)(ws + 36 * MB);             // 16 MB  [bh][d][s]
  short* Og  = (short*)(ws + 52 * MB);             // 16 MB  [b*s][h*d]

  k_prep<<<1536, 256, 0, stream>>>(Wq, Wk, Wv, Wo, rc, rs, WT, WoT);
  k_qkv<<<dim3(32, 32), 256, 0, stream>>>(q, WT, rc, rs, Qg, Kg, Vg);
  k_attn<<<dim3(32, 16), 256, 0, stream>>>(Qg, Kg, Vg, Og);
  hipMemsetAsync(d_out, 0, (size_t)out_size * sizeof(float), stream);
  k_out<<<dim3(32, 4), 256, 0, stream>>>(Og, WoT, out);
}

// Round 4
// 261.203 us; speedup vs baseline: 1.5868x; 1.5868x over previous
//
#include <hip/hip_runtime.h>
#include <math.h>

#define S_LEN 2048
#define NH 16
#define DH 128
#define INNER 2048   // NH*DH
#define NROWS 4096   // B*S

typedef __attribute__((ext_vector_type(8))) short bf16x8;
typedef __attribute__((ext_vector_type(4))) float f32x4;

__device__ __forceinline__ short f2bf(float f) {
  union { float f; unsigned u; } v; v.f = f;
  unsigned r = (v.u + 0x7fffu + ((v.u >> 16) & 1u)) >> 16;
  return (short)(unsigned short)r;
}

// ---------------- fused prep: rope table (transposed [i][s]) + W transposes ----------------
// grid 1536: [0,512) rope table; [512,1280) Wq/Wk/Wv transpose; [1280,1536) Wo
__global__ void k_prep(const float* __restrict__ Wq, const float* __restrict__ Wk,
                       const float* __restrict__ Wv, const float* __restrict__ Wo,
                       float* __restrict__ rcT, float* __restrict__ rsT,
                       short* __restrict__ WT, short* __restrict__ WoT) {
  const int bx = blockIdx.x, tid = threadIdx.x;
  if (bx < 512) {
    int idx = bx * 256 + tid;           // 64 * S_LEN entries, [i][s]
    int i = idx >> 11, s = idx & 2047;
    double invf = pow(10000.0, -(double)i / 64.0);
    float ang = (float)((double)s * invf);
    float sv, cv; sincosf(ang, &sv, &cv);
    rcT[idx] = cv; rsT[idx] = sv;
    return;
  }
  __shared__ float tile[32][33];
  const float* src; short* dst; int R, C, c0, r0;
  if (bx < 1280) {
    int z = (bx - 512) >> 8, t = (bx - 512) & 255;
    src = (z == 0) ? Wq : ((z == 1) ? Wk : Wv);
    dst = WT + (size_t)z * INNER * 128; R = 128; C = INNER;
    c0 = (t & 63) * 32; r0 = (t >> 6) * 32;
  } else {
    int t = bx - 1280;
    src = Wo; dst = WoT; R = INNER; C = 128;
    c0 = (t & 3) * 32; r0 = (t >> 2) * 32;
  }
  int tx = tid & 31, ty = tid >> 5;     // 32 x 8
  #pragma unroll
  for (int dy = 0; dy < 32; dy += 8)
    tile[ty + dy][tx] = src[(size_t)(r0 + ty + dy) * C + c0 + tx];
  __syncthreads();
  #pragma unroll
  for (int dy = 0; dy < 32; dy += 8)
    dst[(size_t)(c0 + ty + dy) * R + r0 + tx] = f2bf(tile[tx][ty + dy]);
}

// ---------------- fused QKV projection + RoPE ----------------
// grid (32 n-tiles, 32 m-tiles), block 256. Q,K [bh][s][d]; V [bh][d][s].
__global__ __launch_bounds__(256) void k_qkv(
    const float* __restrict__ X, const short* __restrict__ WT,
    const float* __restrict__ rcT, const float* __restrict__ rsT,
    short* __restrict__ Qg, short* __restrict__ Kg, short* __restrict__ Vg) {
  __shared__ __attribute__((aligned(16))) short As[128 * 136];
  __shared__ __attribute__((aligned(16))) short Bs[64 * 136];
  const int tid = threadIdx.x;
  const int n0 = blockIdx.x * 64, m0 = blockIdx.y * 128;
  for (int c = tid; c < 128 * 32; c += 256) {
    int row = c >> 5, cj = c & 31;
    float4 xv = *(const float4*)&X[(size_t)(m0 + row) * 128 + cj * 4];
    short4 o; o.x = f2bf(xv.x); o.y = f2bf(xv.y); o.z = f2bf(xv.z); o.w = f2bf(xv.w);
    *(short4*)&As[row * 136 + cj * 4] = o;
  }
  const int wid = tid >> 6, lane = tid & 63;
  const int l16 = lane & 15, quad = lane >> 4;
  const int wm = (wid & 1) * 64, wn = (wid >> 1) * 32;
  const float qscale = 0.08838834764831845f;   // 1/sqrt(128) folded into Q
  for (int z = 0; z < 3; ++z) {
    __syncthreads();   // As ready (z=0) / prior mfma LDS reads done (z>0)
    const short* Wp = WT + (size_t)z * INNER * 128;
    for (int c = tid; c < 64 * 16; c += 256) {
      int row = c >> 4, cj = c & 15;
      *(int4*)&Bs[row * 136 + cj * 8] = *(const int4*)&Wp[(size_t)(n0 + row) * 128 + cj * 8];
    }
    __syncthreads();
    f32x4 acc[4][2] = {};
    #pragma unroll
    for (int ks = 0; ks < 4; ++ks) {
      bf16x8 a[4], b[2];
      #pragma unroll
      for (int mt = 0; mt < 4; ++mt)
        a[mt] = *(const bf16x8*)&As[(wm + mt * 16 + l16) * 136 + ks * 32 + quad * 8];
      #pragma unroll
      for (int nt = 0; nt < 2; ++nt)
        b[nt] = *(const bf16x8*)&Bs[(wn + nt * 16 + l16) * 136 + ks * 32 + quad * 8];
      #pragma unroll
      for (int mt = 0; mt < 4; ++mt)
        #pragma unroll
        for (int nt = 0; nt < 2; ++nt)
          acc[mt][nt] = __builtin_amdgcn_mfma_f32_16x16x32_bf16(a[mt], b[nt], acc[mt][nt], 0, 0, 0);
    }
    if (z < 2) {
      #pragma unroll
      for (int mt = 0; mt < 4; ++mt)
        #pragma unroll
        for (int nt = 0; nt < 2; ++nt) {
          int gn = n0 + wn + nt * 16 + l16;
          int h = gn >> 7, d = gn & 127, i = d >> 1;
          int gm0 = m0 + wm + mt * 16 + quad * 4;
          int bb = gm0 >> 11, s0 = gm0 & 2047;
          // cos/sin as vector loads from transposed tables [i][s]
          float4 c4 = *(const float4*)&rcT[i * S_LEN + s0];
          float4 s4 = *(const float4*)&rsT[i * S_LEN + s0];
          float cA[4] = {c4.x, c4.y, c4.z, c4.w};
          float sA[4] = {s4.x, s4.y, s4.z, s4.w};
          #pragma unroll
          for (int r = 0; r < 4; ++r) {
            float v = acc[mt][nt][r];
            float pv = __shfl_xor(v, 1);          // partner lane holds d^1
            float res = (d & 1) ? (v * cA[r] + pv * sA[r]) : (v * cA[r] - pv * sA[r]);
            if (z == 0) res *= qscale;
            size_t off = (((size_t)(bb * NH + h)) * S_LEN + s0 + r) * DH + d;
            short bv = f2bf(res);
            if (z == 0) Qg[off] = bv; else Kg[off] = bv;
          }
        }
    } else {
      #pragma unroll
      for (int mt = 0; mt < 4; ++mt)
        #pragma unroll
        for (int nt = 0; nt < 2; ++nt) {
          int gn = n0 + wn + nt * 16 + l16;
          int h = gn >> 7, d = gn & 127;
          int gmb = m0 + wm + mt * 16 + quad * 4;
          int bb = gmb >> 11, s = gmb & 2047;
          short4 pk;
          pk.x = f2bf(acc[mt][nt][0]); pk.y = f2bf(acc[mt][nt][1]);
          pk.z = f2bf(acc[mt][nt][2]); pk.w = f2bf(acc[mt][nt][3]);
          *(short4*)&Vg[(((size_t)(bb * NH + h)) * DH + d) * S_LEN + s] = pk;
        }
    }
  }
}

// ---------------- flash attention: 128-q blocks, dbuf LDS, 1 barrier/iter ----------
// grid (32 bh, 8 pairs), block 256 (4 waves x 32 q-rows = 128-q tile).
// Pairs (g, 15-g): uniform 34 KV-tile iterations; 256 blocks = 1/CU.
// XCD = bh % 8 -> 4 bh per XCD, K+V working set 4 MB = L2 size.
// K/V double-buffered in LDS (one __syncthreads per iter), staging loads
// register-prefetched one tile ahead. Q fragments live in registers.
__global__ __launch_bounds__(256, 1) void k_attn(
    const short* __restrict__ Qg, const short* __restrict__ Kg,
    const short* __restrict__ Vg, short* __restrict__ Og) {
  __shared__ __attribute__((aligned(16))) short Ks[2][64 * 136];   // [t][d]
  __shared__ __attribute__((aligned(16))) short Vs[2][128 * 72];   // [d][t]
  __shared__ __attribute__((aligned(16))) short Ps[4][32 * 72];    // per-wave [q][t]
  const int bh = blockIdx.x, p = blockIdx.y;
  const int bb = bh >> 4, h = bh & 15;
  const int tid = threadIdx.x, wid = tid >> 6, lane = tid & 63;
  const int l16 = lane & 15, quad = lane >> 4, wq = wid * 32;
  const short* Qp = Qg + (size_t)bh * S_LEN * DH;   // [s][d]
  const short* Kp = Kg + (size_t)bh * S_LEN * DH;   // [s][d]
  const short* Vp = Vg + (size_t)bh * S_LEN * DH;   // [d][s]
  short* psw = &Ps[wid][0];
  int4 kr[4], vr[4];

  for (int ph = 0; ph < 2; ++ph) {
    const int g = ph ? (15 - p) : p;
    const int q0 = g * 128;
    const int jmax = 2 * g + 2;
    // Q fragments -> registers for the whole phase
    bf16x8 qf[4][2];
    #pragma unroll
    for (int ks = 0; ks < 4; ++ks)
      #pragma unroll
      for (int qb = 0; qb < 2; ++qb)
        qf[ks][qb] = *(const bf16x8*)&Qp[(size_t)(q0 + wq + qb * 16 + l16) * DH +
                                         ks * 32 + quad * 8];
    // stage tile 0 into buffer 0
    #pragma unroll
    for (int i = 0; i < 4; ++i) {
      int e = tid + 256 * i;
      kr[i] = *(const int4*)&Kp[(size_t)(e >> 4) * DH + (e & 15) * 8];
      vr[i] = *(const int4*)&Vp[(size_t)(e >> 3) * S_LEN + (e & 7) * 8];
    }
    #pragma unroll
    for (int i = 0; i < 4; ++i) {
      int e = tid + 256 * i;
      *(int4*)&Ks[0][(e >> 4) * 136 + (e & 15) * 8] = kr[i];
      *(int4*)&Vs[0][(e >> 3) * 72 + (e & 7) * 8] = vr[i];
    }
    float m_i[2] = {-1e30f, -1e30f}, l_i[2] = {0.0f, 0.0f};
    f32x4 Oacc[8][2] = {};
    __syncthreads();
    for (int j = 0; j < jmax; ++j) {
      const int b = j & 1;
      if (j + 1 < jmax) {   // register-prefetch next tile (in flight during compute)
        #pragma unroll
        for (int i = 0; i < 4; ++i) {
          int e = tid + 256 * i;
          kr[i] = *(const int4*)&Kp[(size_t)((j + 1) * 64 + (e >> 4)) * DH + (e & 15) * 8];
          vr[i] = *(const int4*)&Vp[(size_t)(e >> 3) * S_LEN + (j + 1) * 64 + (e & 7) * 8];
        }
      }
      // S^T = K @ Q^T : per wave t=64 x q=32
      f32x4 Sc[4][2] = {};
      #pragma unroll
      for (int ks = 0; ks < 4; ++ks) {
        bf16x8 kfr[4];
        #pragma unroll
        for (int nt = 0; nt < 4; ++nt)
          kfr[nt] = *(const bf16x8*)&Ks[b][(nt * 16 + l16) * 136 + ks * 32 + quad * 8];
        #pragma unroll
        for (int nt = 0; nt < 4; ++nt)
          #pragma unroll
          for (int qb = 0; qb < 2; ++qb)
            Sc[nt][qb] = __builtin_amdgcn_mfma_f32_16x16x32_bf16(kfr[nt], qf[ks][qb],
                                                                 Sc[nt][qb], 0, 0, 0);
      }
      if (j >= 2 * g) {   // causal mask near diagonal
        #pragma unroll
        for (int nt = 0; nt < 4; ++nt)
          #pragma unroll
          for (int qb = 0; qb < 2; ++qb)
            #pragma unroll
            for (int r = 0; r < 4; ++r) {
              int tg = j * 64 + nt * 16 + quad * 4 + r;
              int qg = q0 + wq + qb * 16 + l16;
              if (tg > qg) Sc[nt][qb][r] = -1e30f;
            }
      }
      // online softmax over t, per q-halftile
      #pragma unroll
      for (int qb = 0; qb < 2; ++qb) {
        float mloc = -1e30f;
        #pragma unroll
        for (int nt = 0; nt < 4; ++nt)
          #pragma unroll
          for (int r = 0; r < 4; ++r) mloc = fmaxf(mloc, Sc[nt][qb][r]);
        mloc = fmaxf(mloc, __shfl_xor(mloc, 16));
        mloc = fmaxf(mloc, __shfl_xor(mloc, 32));
        float mnew = fmaxf(m_i[qb], mloc);
        float alpha = __expf(m_i[qb] - mnew);
        m_i[qb] = mnew;
        float rsum = 0.0f;
        #pragma unroll
        for (int nt = 0; nt < 4; ++nt)
          #pragma unroll
          for (int r = 0; r < 4; ++r) {
            float pe = __expf(Sc[nt][qb][r] - mnew);
            Sc[nt][qb][r] = pe;
            rsum += pe;
          }
        rsum += __shfl_xor(rsum, 16);
        rsum += __shfl_xor(rsum, 32);
        l_i[qb] = l_i[qb] * alpha + rsum;
        #pragma unroll
        for (int nt = 0; nt < 8; ++nt)
          #pragma unroll
          for (int r = 0; r < 4; ++r) Oacc[nt][qb][r] *= alpha;
        // P^T -> wave-private LDS slab (C-layout -> B-operand layout)
        #pragma unroll
        for (int nt = 0; nt < 4; ++nt) {
          short4 pk;
          pk.x = f2bf(Sc[nt][qb][0]); pk.y = f2bf(Sc[nt][qb][1]);
          pk.z = f2bf(Sc[nt][qb][2]); pk.w = f2bf(Sc[nt][qb][3]);
          *(short4*)&psw[(qb * 16 + l16) * 72 + nt * 16 + quad * 4] = pk;
        }
      }
      // O^T += V^T @ P
      #pragma unroll
      for (int ks = 0; ks < 2; ++ks) {
        bf16x8 vfr[8];
        #pragma unroll
        for (int nt = 0; nt < 8; ++nt)
          vfr[nt] = *(const bf16x8*)&Vs[b][(nt * 16 + l16) * 72 + ks * 32 + quad * 8];
        bf16x8 bp[2];
        #pragma unroll
        for (int qb = 0; qb < 2; ++qb)
          bp[qb] = *(const bf16x8*)&psw[(qb * 16 + l16) * 72 + ks * 32 + quad * 8];
        #pragma unroll
        for (int nt = 0; nt < 8; ++nt)
          #pragma unroll
          for (int qb = 0; qb < 2; ++qb)
            Oacc[nt][qb] = __builtin_amdgcn_mfma_f32_16x16x32_bf16(vfr[nt], bp[qb],
                                                                   Oacc[nt][qb], 0, 0, 0);
      }
      // store prefetched tile into the other buffer (its readers synced last iter)
      if (j + 1 < jmax) {
        #pragma unroll
        for (int i = 0; i < 4; ++i) {
          int e = tid + 256 * i;
          *(int4*)&Ks[1 - b][(e >> 4) * 136 + (e & 15) * 8] = kr[i];
          *(int4*)&Vs[1 - b][(e >> 3) * 72 + (e & 7) * 8] = vr[i];
        }
      }
      __syncthreads();
    }
    // write O^T: Oacc[nt][qb][r] = O[q=q0+wq+qb*16+l16][d=nt*16+quad*4+r] / l
    #pragma unroll
    for (int qb = 0; qb < 2; ++qb) {
      float inv = 1.0f / l_i[qb];
      size_t orow = ((size_t)(bb * S_LEN + q0 + wq + qb * 16 + l16)) * INNER + h * DH;
      #pragma unroll
      for (int nt = 0; nt < 8; ++nt) {
        short4 ov;
        ov.x = f2bf(Oacc[nt][qb][0] * inv); ov.y = f2bf(Oacc[nt][qb][1] * inv);
        ov.z = f2bf(Oacc[nt][qb][2] * inv); ov.w = f2bf(Oacc[nt][qb][3] * inv);
        *(short4*)&Og[orow + nt * 16 + quad * 4] = ov;
      }
    }
  }
}

// ---------------- output projection: Og[4096,2048] @ Wo[2048,128] ----------------
__global__ __launch_bounds__(256) void k_out(
    const short* __restrict__ Og, const short* __restrict__ WoT,
    float* __restrict__ out) {
  __shared__ __attribute__((aligned(16))) short As[128 * 72];
  __shared__ __attribute__((aligned(16))) short Bs[128 * 72];
  const int m0 = blockIdx.x * 128, kb0 = blockIdx.y * 512;
  const int tid = threadIdx.x, wid = tid >> 6, lane = tid & 63;
  const int l16 = lane & 15, quad = lane >> 4;
  const int wm = (wid & 1) * 64, wn = (wid >> 1) * 64;
  f32x4 acc[4][4] = {};
  for (int kc = 0; kc < 8; ++kc) {
    int k0 = kb0 + kc * 64;
    for (int c = tid; c < 128 * 8; c += 256) {
      int row = c >> 3, cj = c & 7;
      *(int4*)&As[row * 72 + cj * 8] =
          *(const int4*)&Og[(size_t)(m0 + row) * INNER + k0 + cj * 8];
    }
    for (int c = tid; c < 128 * 8; c += 256) {
      int row = c >> 3, cj = c & 7;
      *(int4*)&Bs[row * 72 + cj * 8] =
          *(const int4*)&WoT[(size_t)row * INNER + k0 + cj * 8];
    }
    __syncthreads();
    #pragma unroll
    for (int ks = 0; ks < 2; ++ks) {
      bf16x8 a[4], b[4];
      #pragma unroll
      for (int mt = 0; mt < 4; ++mt)
        a[mt] = *(const bf16x8*)&As[(wm + mt * 16 + l16) * 72 + ks * 32 + quad * 8];
      #pragma unroll
      for (int nt = 0; nt < 4; ++nt)
        b[nt] = *(const bf16x8*)&Bs[(wn + nt * 16 + l16) * 72 + ks * 32 + quad * 8];
      #pragma unroll
      for (int mt = 0; mt < 4; ++mt)
        #pragma unroll
        for (int nt = 0; nt < 4; ++nt)
          acc[mt][nt] = __builtin_amdgcn_mfma_f32_16x16x32_bf16(a[mt], b[nt], acc[mt][nt], 0, 0, 0);
    }
    __syncthreads();
  }
  #pragma unroll
  for (int mt = 0; mt < 4; ++mt)
    #pragma unroll
    for (int nt = 0; nt < 4; ++nt)
      #pragma unroll
      for (int r = 0; r < 4; ++r) {
        int gm = m0 + wm + mt * 16 + quad * 4 + r;
        int gn = wn + nt * 16 + l16;
        atomicAdd(&out[(size_t)gm * 128 + gn], acc[mt][nt][r]);
      }
}

// ---------------- launch ----------------
extern "C" void kernel_launch(void* const* d_in, const int* in_sizes, int n_in,
                              void* d_out, int out_size, void* d_ws, size_t ws_size,
                              hipStream_t stream) {
  const float* q  = (const float*)d_in[0];
  const float* Wq = (const float*)d_in[1];
  const float* Wk = (const float*)d_in[2];
  const float* Wv = (const float*)d_in[3];
  const float* Wo = (const float*)d_in[4];
  float* out = (float*)d_out;
  char* ws = (char*)d_ws;
  const size_t MB = 1024 * 1024;
  float* rcT = (float*)(ws + 0);                   // 512 KB  [i][s]
  float* rsT = (float*)(ws + 512 * 1024);          // 512 KB  [i][s]
  short* WT  = (short*)(ws + 1 * MB);              // 1.5 MB (Wq,Wk,Wv [n][k] bf16)
  short* WoT = (short*)(ws + 2 * MB + 512 * 1024); // 512 KB
  short* Qg  = (short*)(ws + 4 * MB);              // 16 MB  [bh][s][d]
  short* Kg  = (short*)(ws + 20 * MB);             // 16 MB  [bh][s][d]
  short* Vg  = (short*)(ws + 36 * MB);             // 16 MB  [bh][d][s]
  short* Og  = (short*)(ws + 52 * MB);             // 16 MB  [b*s][h*d]

  k_prep<<<1536, 256, 0, stream>>>(Wq, Wk, Wv, Wo, rcT, rsT, WT, WoT);
  k_qkv<<<dim3(32, 32), 256, 0, stream>>>(q, WT, rcT, rsT, Qg, Kg, Vg);
  k_attn<<<dim3(32, 8), 256, 0, stream>>>(Qg, Kg, Vg, Og);
  hipMemsetAsync(d_out, 0, (size_t)out_size * sizeof(float), stream);
  k_out<<<dim3(32, 4), 256, 0, stream>>>(Og, WoT, out);
}

// Round 5
// 253.985 us; speedup vs baseline: 1.6319x; 1.0284x over previous
//
#include <hip/hip_runtime.h>
#include <math.h>

#define S_LEN 2048
#define NH 16
#define DH 128
#define INNER 2048   // NH*DH
#define NROWS 4096   // B*S

typedef __attribute__((ext_vector_type(8))) short bf16x8;
typedef __attribute__((ext_vector_type(4))) float f32x4;

__device__ __forceinline__ short f2bf(float f) {
  union { float f; unsigned u; } v; v.f = f;
  unsigned r = (v.u + 0x7fffu + ((v.u >> 16) & 1u)) >> 16;
  return (short)(unsigned short)r;
}

// ---------------- fused prep ----------------
// grid 2048: [0,512) rope table [i][s]; [512,1024) X fp32->bf16;
//            [1024,1792) Wq/Wk/Wv transpose; [1792,2048) Wo transpose
__global__ void k_prep(const float* __restrict__ X, const float* __restrict__ Wq,
                       const float* __restrict__ Wk, const float* __restrict__ Wv,
                       const float* __restrict__ Wo,
                       float* __restrict__ rcT, float* __restrict__ rsT,
                       short* __restrict__ Xbf, short* __restrict__ WT,
                       short* __restrict__ WoT) {
  const int bx = blockIdx.x, tid = threadIdx.x;
  if (bx < 512) {
    int idx = bx * 256 + tid;           // 64 * S_LEN entries, [i][s]
    int i = idx >> 11, s = idx & 2047;
    double invf = pow(10000.0, -(double)i / 64.0);
    float ang = (float)((double)s * invf);
    float sv, cv; sincosf(ang, &sv, &cv);
    rcT[idx] = cv; rsT[idx] = sv;
    return;
  }
  if (bx < 1024) {
    int idx = ((bx - 512) * 256 + tid) * 4;
    float4 xv = *(const float4*)&X[idx];
    short4 o; o.x = f2bf(xv.x); o.y = f2bf(xv.y); o.z = f2bf(xv.z); o.w = f2bf(xv.w);
    *(short4*)&Xbf[idx] = o;
    return;
  }
  __shared__ float tile[32][33];
  const float* src; short* dst; int R, C, c0, r0;
  if (bx < 1792) {
    int z = (bx - 1024) >> 8, t = (bx - 1024) & 255;
    src = (z == 0) ? Wq : ((z == 1) ? Wk : Wv);
    dst = WT + (size_t)z * INNER * 128; R = 128; C = INNER;
    c0 = (t & 63) * 32; r0 = (t >> 6) * 32;
  } else {
    int t = bx - 1792;
    src = Wo; dst = WoT; R = INNER; C = 128;
    c0 = (t & 3) * 32; r0 = (t >> 2) * 32;
  }
  int tx = tid & 31, ty = tid >> 5;     // 32 x 8
  #pragma unroll
  for (int dy = 0; dy < 32; dy += 8)
    tile[ty + dy][tx] = src[(size_t)(r0 + ty + dy) * C + c0 + tx];
  __syncthreads();
  #pragma unroll
  for (int dy = 0; dy < 32; dy += 8)
    dst[(size_t)(c0 + ty + dy) * R + r0 + tx] = f2bf(tile[tx][ty + dy]);
}

// ---------------- fused QKV projection + RoPE ----------------
// grid (16 n-tiles of 128, 32 m-tiles of 128) = 512 blocks = 2/CU.
// Q,K [bh][s][d]; V [bh][d][s] (transposed packed stores).
__global__ __launch_bounds__(256, 2) void k_qkv(
    const short* __restrict__ Xbf, const short* __restrict__ WT,
    const float* __restrict__ rcT, const float* __restrict__ rsT,
    short* __restrict__ Qg, short* __restrict__ Kg, short* __restrict__ Vg) {
  __shared__ __attribute__((aligned(16))) short As[128 * 136];
  __shared__ __attribute__((aligned(16))) short Bs[128 * 136];
  const int tid = threadIdx.x;
  const int n0 = blockIdx.x * 128, m0 = blockIdx.y * 128;
  for (int e = tid; e < 2048; e += 256)
    *(int4*)&As[(e >> 4) * 136 + (e & 15) * 8] =
        *(const int4*)&Xbf[(size_t)(m0 + (e >> 4)) * 128 + (e & 15) * 8];
  const int wid = tid >> 6, lane = tid & 63;
  const int l16 = lane & 15, quad = lane >> 4;
  const int wm = (wid & 1) * 64, wn = (wid >> 1) * 64;
  const float qscale = 0.08838834764831845f;   // 1/sqrt(128) folded into Q
  for (int z = 0; z < 3; ++z) {
    __syncthreads();   // As ready (z=0) / prior MFMA LDS reads done (z>0)
    const short* Wp = WT + (size_t)z * INNER * 128;
    for (int e = tid; e < 2048; e += 256)
      *(int4*)&Bs[(e >> 4) * 136 + (e & 15) * 8] =
          *(const int4*)&Wp[(size_t)(n0 + (e >> 4)) * 128 + (e & 15) * 8];
    __syncthreads();
    f32x4 acc[4][4] = {};
    #pragma unroll
    for (int ks = 0; ks < 4; ++ks) {
      bf16x8 a[4], b[4];
      #pragma unroll
      for (int mt = 0; mt < 4; ++mt)
        a[mt] = *(const bf16x8*)&As[(wm + mt * 16 + l16) * 136 + ks * 32 + quad * 8];
      #pragma unroll
      for (int nt = 0; nt < 4; ++nt)
        b[nt] = *(const bf16x8*)&Bs[(wn + nt * 16 + l16) * 136 + ks * 32 + quad * 8];
      #pragma unroll
      for (int mt = 0; mt < 4; ++mt)
        #pragma unroll
        for (int nt = 0; nt < 4; ++nt)
          acc[mt][nt] = __builtin_amdgcn_mfma_f32_16x16x32_bf16(a[mt], b[nt], acc[mt][nt], 0, 0, 0);
    }
    if (z < 2) {
      #pragma unroll
      for (int mt = 0; mt < 4; ++mt)
        #pragma unroll
        for (int nt = 0; nt < 4; ++nt) {
          int gn = n0 + wn + nt * 16 + l16;
          int h = gn >> 7, d = gn & 127, i = d >> 1;
          int gm0 = m0 + wm + mt * 16 + quad * 4;
          int bb = gm0 >> 11, s0 = gm0 & 2047;
          float4 c4 = *(const float4*)&rcT[i * S_LEN + s0];
          float4 s4 = *(const float4*)&rsT[i * S_LEN + s0];
          float cA[4] = {c4.x, c4.y, c4.z, c4.w};
          float sA[4] = {s4.x, s4.y, s4.z, s4.w};
          #pragma unroll
          for (int r = 0; r < 4; ++r) {
            float v = acc[mt][nt][r];
            float pv = __shfl_xor(v, 1);          // partner lane holds d^1
            float res = (d & 1) ? (v * cA[r] + pv * sA[r]) : (v * cA[r] - pv * sA[r]);
            if (z == 0) res *= qscale;
            size_t off = (((size_t)(bb * NH + h)) * S_LEN + s0 + r) * DH + d;
            short bv = f2bf(res);
            if (z == 0) Qg[off] = bv; else Kg[off] = bv;
          }
        }
    } else {
      #pragma unroll
      for (int mt = 0; mt < 4; ++mt)
        #pragma unroll
        for (int nt = 0; nt < 4; ++nt) {
          int gn = n0 + wn + nt * 16 + l16;
          int h = gn >> 7, d = gn & 127;
          int gmb = m0 + wm + mt * 16 + quad * 4;
          int bb = gmb >> 11, s = gmb & 2047;
          short4 pk;
          pk.x = f2bf(acc[mt][nt][0]); pk.y = f2bf(acc[mt][nt][1]);
          pk.z = f2bf(acc[mt][nt][2]); pk.w = f2bf(acc[mt][nt][3]);
          *(short4*)&Vg[(((size_t)(bb * NH + h)) * DH + d) * S_LEN + s] = pk;
        }
    }
  }
}

// ---------------- flash attention: 128-q blocks, 2 blocks/CU ----------------
// 512 1D blocks (256 threads). Decode: lo=bid&255, hi=bid>>8; bh=lo&31,
// g = hi ? 15-(lo>>5) : lo>>5. Blocks bid and bid+256 share bh with
// complementary g (work 2g+2 + 2(15-g)+2 = 36) -> same-CU pairing balances
// load; XCD = bid%8 correlates with bh%8 -> K/V L2 locality (4 bh/XCD).
// LDS 70 KB (K dbuf + V single + per-wave Ps) -> 2 blocks/CU so the second
// block's waves cover this block's barrier/softmax stalls (m114 overlap).
__global__ __launch_bounds__(256, 2) void k_attn(
    const short* __restrict__ Qg, const short* __restrict__ Kg,
    const short* __restrict__ Vg, short* __restrict__ Og) {
  __shared__ __attribute__((aligned(16))) short Ks[2][64 * 136];   // [t][d] dbuf
  __shared__ __attribute__((aligned(16))) short Vs[128 * 72];      // [d][t] single
  __shared__ __attribute__((aligned(16))) short Ps[4][32 * 72];    // per-wave [q][t]
  const int bid = blockIdx.x;
  const int lo = bid & 255, hi = bid >> 8;
  const int bh = lo & 31, qi = lo >> 5;
  const int g = hi ? (15 - qi) : qi;
  const int bb = bh >> 4, h = bh & 15;
  const int tid = threadIdx.x, wid = tid >> 6, lane = tid & 63;
  const int l16 = lane & 15, quad = lane >> 4, wq = wid * 32;
  const int q0 = g * 128, jmax = 2 * g + 2;
  const short* Qp = Qg + (size_t)bh * S_LEN * DH;   // [s][d]
  const short* Kp = Kg + (size_t)bh * S_LEN * DH;   // [s][d]
  const short* Vp = Vg + (size_t)bh * S_LEN * DH;   // [d][s]
  short* psw = &Ps[wid][0];
  int4 kr[4], vr[4];

  // Q fragments -> registers for the whole kernel
  bf16x8 qf[4][2];
  #pragma unroll
  for (int ks = 0; ks < 4; ++ks)
    #pragma unroll
    for (int qb = 0; qb < 2; ++qb)
      qf[ks][qb] = *(const bf16x8*)&Qp[(size_t)(q0 + wq + qb * 16 + l16) * DH +
                                       ks * 32 + quad * 8];
  // stage tile 0
  #pragma unroll
  for (int i = 0; i < 4; ++i) {
    int e = tid + 256 * i;
    kr[i] = *(const int4*)&Kp[(size_t)(e >> 4) * DH + (e & 15) * 8];
    vr[i] = *(const int4*)&Vp[(size_t)(e >> 3) * S_LEN + (e & 7) * 8];
  }
  #pragma unroll
  for (int i = 0; i < 4; ++i) {
    int e = tid + 256 * i;
    *(int4*)&Ks[0][(e >> 4) * 136 + (e & 15) * 8] = kr[i];
    *(int4*)&Vs[(e >> 3) * 72 + (e & 7) * 8] = vr[i];
  }
  float m_i[2] = {-1e30f, -1e30f}, l_i[2] = {0.0f, 0.0f};
  f32x4 Oacc[8][2] = {};
  __syncthreads();
  for (int j = 0; j < jmax; ++j) {
    const int b = j & 1;
    if (j + 1 < jmax) {   // register-prefetch next K/V (in flight all iter)
      #pragma unroll
      for (int i = 0; i < 4; ++i) {
        int e = tid + 256 * i;
        kr[i] = *(const int4*)&Kp[(size_t)((j + 1) * 64 + (e >> 4)) * DH + (e & 15) * 8];
        vr[i] = *(const int4*)&Vp[(size_t)(e >> 3) * S_LEN + (j + 1) * 64 + (e & 7) * 8];
      }
    }
    // S^T = K @ Q^T : per wave t=64 x q=32
    f32x4 Sc[4][2] = {};
    #pragma unroll
    for (int ks = 0; ks < 4; ++ks) {
      bf16x8 kfr[4];
      #pragma unroll
      for (int nt = 0; nt < 4; ++nt)
        kfr[nt] = *(const bf16x8*)&Ks[b][(nt * 16 + l16) * 136 + ks * 32 + quad * 8];
      #pragma unroll
      for (int nt = 0; nt < 4; ++nt)
        #pragma unroll
        for (int qb = 0; qb < 2; ++qb)
          Sc[nt][qb] = __builtin_amdgcn_mfma_f32_16x16x32_bf16(kfr[nt], qf[ks][qb],
                                                               Sc[nt][qb], 0, 0, 0);
    }
    if (j >= 2 * g) {   // causal mask near diagonal
      #pragma unroll
      for (int nt = 0; nt < 4; ++nt)
        #pragma unroll
        for (int qb = 0; qb < 2; ++qb)
          #pragma unroll
          for (int r = 0; r < 4; ++r) {
            int tg = j * 64 + nt * 16 + quad * 4 + r;
            int qg = q0 + wq + qb * 16 + l16;
            if (tg > qg) Sc[nt][qb][r] = -1e30f;
          }
    }
    // online softmax over t, per q-halftile
    #pragma unroll
    for (int qb = 0; qb < 2; ++qb) {
      float mloc = -1e30f;
      #pragma unroll
      for (int nt = 0; nt < 4; ++nt)
        #pragma unroll
        for (int r = 0; r < 4; ++r) mloc = fmaxf(mloc, Sc[nt][qb][r]);
      mloc = fmaxf(mloc, __shfl_xor(mloc, 16));
      mloc = fmaxf(mloc, __shfl_xor(mloc, 32));
      float mnew = fmaxf(m_i[qb], mloc);
      float alpha = __expf(m_i[qb] - mnew);
      m_i[qb] = mnew;
      float rsum = 0.0f;
      #pragma unroll
      for (int nt = 0; nt < 4; ++nt)
        #pragma unroll
        for (int r = 0; r < 4; ++r) {
          float pe = __expf(Sc[nt][qb][r] - mnew);
          Sc[nt][qb][r] = pe;
          rsum += pe;
        }
      rsum += __shfl_xor(rsum, 16);
      rsum += __shfl_xor(rsum, 32);
      l_i[qb] = l_i[qb] * alpha + rsum;
      #pragma unroll
      for (int nt = 0; nt < 8; ++nt)
        #pragma unroll
        for (int r = 0; r < 4; ++r) Oacc[nt][qb][r] *= alpha;
      // P^T -> wave-private LDS slab (C-layout -> B-operand layout)
      #pragma unroll
      for (int nt = 0; nt < 4; ++nt) {
        short4 pk;
        pk.x = f2bf(Sc[nt][qb][0]); pk.y = f2bf(Sc[nt][qb][1]);
        pk.z = f2bf(Sc[nt][qb][2]); pk.w = f2bf(Sc[nt][qb][3]);
        *(short4*)&psw[(qb * 16 + l16) * 72 + nt * 16 + quad * 4] = pk;
      }
    }
    // O^T += V^T @ P  (V tile j from single-buffered Vs)
    #pragma unroll
    for (int ks = 0; ks < 2; ++ks) {
      bf16x8 vfr[8];
      #pragma unroll
      for (int nt = 0; nt < 8; ++nt)
        vfr[nt] = *(const bf16x8*)&Vs[(nt * 16 + l16) * 72 + ks * 32 + quad * 8];
      bf16x8 bp[2];
      #pragma unroll
      for (int qb = 0; qb < 2; ++qb)
        bp[qb] = *(const bf16x8*)&psw[(qb * 16 + l16) * 72 + ks * 32 + quad * 8];
      #pragma unroll
      for (int nt = 0; nt < 8; ++nt)
        #pragma unroll
        for (int qb = 0; qb < 2; ++qb)
          Oacc[nt][qb] = __builtin_amdgcn_mfma_f32_16x16x32_bf16(vfr[nt], bp[qb],
                                                                 Oacc[nt][qb], 0, 0, 0);
    }
    __syncthreads();    // PV reads of Vs / QK reads of Ks[b] complete
    if (j + 1 < jmax) {
      #pragma unroll
      for (int i = 0; i < 4; ++i) {
        int e = tid + 256 * i;
        *(int4*)&Ks[1 - b][(e >> 4) * 136 + (e & 15) * 8] = kr[i];
        *(int4*)&Vs[(e >> 3) * 72 + (e & 7) * 8] = vr[i];
      }
    }
    __syncthreads();    // staged writes visible before next iter's reads
  }
  // write O^T: Oacc[nt][qb][r] = O[q=q0+wq+qb*16+l16][d=nt*16+quad*4+r] / l
  #pragma unroll
  for (int qb = 0; qb < 2; ++qb) {
    float inv = 1.0f / l_i[qb];
    size_t orow = ((size_t)(bb * S_LEN + q0 + wq + qb * 16 + l16)) * INNER + h * DH;
    #pragma unroll
    for (int nt = 0; nt < 8; ++nt) {
      short4 ov;
      ov.x = f2bf(Oacc[nt][qb][0] * inv); ov.y = f2bf(Oacc[nt][qb][1] * inv);
      ov.z = f2bf(Oacc[nt][qb][2] * inv); ov.w = f2bf(Oacc[nt][qb][3] * inv);
      *(short4*)&Og[orow + nt * 16 + quad * 4] = ov;
    }
  }
}

// ---------------- output projection: Og[4096,2048] @ Wo[2048,128] ----------------
// grid (64 m-tiles of 64, splitK 4) = 256 blocks = 1/CU; atomicAdd into zeroed out.
__global__ __launch_bounds__(256) void k_out(
    const short* __restrict__ Og, const short* __restrict__ WoT,
    float* __restrict__ out) {
  __shared__ __attribute__((aligned(16))) short As[64 * 72];
  __shared__ __attribute__((aligned(16))) short Bs[128 * 72];
  const int m0 = blockIdx.x * 64, kb0 = blockIdx.y * 512;
  const int tid = threadIdx.x, wid = tid >> 6, lane = tid & 63;
  const int l16 = lane & 15, quad = lane >> 4;
  const int wm = (wid & 1) * 32, wn = (wid >> 1) * 64;
  f32x4 acc[2][4] = {};
  for (int kc = 0; kc < 8; ++kc) {
    int k0 = kb0 + kc * 64;
    for (int e = tid; e < 512; e += 256)
      *(int4*)&As[(e >> 3) * 72 + (e & 7) * 8] =
          *(const int4*)&Og[(size_t)(m0 + (e >> 3)) * INNER + k0 + (e & 7) * 8];
    for (int e = tid; e < 1024; e += 256)
      *(int4*)&Bs[(e >> 3) * 72 + (e & 7) * 8] =
          *(const int4*)&WoT[(size_t)(e >> 3) * INNER + k0 + (e & 7) * 8];
    __syncthreads();
    #pragma unroll
    for (int ks = 0; ks < 2; ++ks) {
      bf16x8 a[2], b[4];
      #pragma unroll
      for (int mt = 0; mt < 2; ++mt)
        a[mt] = *(const bf16x8*)&As[(wm + mt * 16 + l16) * 72 + ks * 32 + quad * 8];
      #pragma unroll
      for (int nt = 0; nt < 4; ++nt)
        b[nt] = *(const bf16x8*)&Bs[(wn + nt * 16 + l16) * 72 + ks * 32 + quad * 8];
      #pragma unroll
      for (int mt = 0; mt < 2; ++mt)
        #pragma unroll
        for (int nt = 0; nt < 4; ++nt)
          acc[mt][nt] = __builtin_amdgcn_mfma_f32_16x16x32_bf16(a[mt], b[nt], acc[mt][nt], 0, 0, 0);
    }
    __syncthreads();
  }
  #pragma unroll
  for (int mt = 0; mt < 2; ++mt)
    #pragma unroll
    for (int nt = 0; nt < 4; ++nt)
      #pragma unroll
      for (int r = 0; r < 4; ++r) {
        int gm = m0 + wm + mt * 16 + quad * 4 + r;
        int gn = wn + nt * 16 + l16;
        atomicAdd(&out[(size_t)gm * 128 + gn], acc[mt][nt][r]);
      }
}

// ---------------- launch ----------------
extern "C" void kernel_launch(void* const* d_in, const int* in_sizes, int n_in,
                              void* d_out, int out_size, void* d_ws, size_t ws_size,
                              hipStream_t stream) {
  const float* q  = (const float*)d_in[0];
  const float* Wq = (const float*)d_in[1];
  const float* Wk = (const float*)d_in[2];
  const float* Wv = (const float*)d_in[3];
  const float* Wo = (const float*)d_in[4];
  float* out = (float*)d_out;
  char* ws = (char*)d_ws;
  const size_t MB = 1024 * 1024;
  float* rcT = (float*)(ws + 0);                   // 512 KB  [i][s]
  float* rsT = (float*)(ws + 512 * 1024);          // 512 KB  [i][s]
  short* WT  = (short*)(ws + 1 * MB);              // 1.5 MB (Wq,Wk,Wv [n][k] bf16)
  short* WoT = (short*)(ws + 2 * MB + 512 * 1024); // 512 KB
  short* Xbf = (short*)(ws + 3 * MB);              // 2 MB   [b*s][e] bf16
  short* Qg  = (short*)(ws + 8 * MB);              // 16 MB  [bh][s][d]
  short* Kg  = (short*)(ws + 24 * MB);             // 16 MB  [bh][s][d]
  short* Vg  = (short*)(ws + 40 * MB);             // 16 MB  [bh][d][s]
  short* Og  = (short*)(ws + 56 * MB);             // 16 MB  [b*s][h*d]

  k_prep<<<2048, 256, 0, stream>>>(q, Wq, Wk, Wv, Wo, rcT, rsT, Xbf, WT, WoT);
  k_qkv<<<dim3(16, 32), 256, 0, stream>>>(Xbf, WT, rcT, rsT, Qg, Kg, Vg);
  k_attn<<<512, 256, 0, stream>>>(Qg, Kg, Vg, Og);
  hipMemsetAsync(d_out, 0, (size_t)out_size * sizeof(float), stream);
  k_out<<<dim3(64, 4), 256, 0, stream>>>(Og, WoT, out);
}

// Round 6
// 229.467 us; speedup vs baseline: 1.8063x; 1.1068x over previous
//
#include <hip/hip_runtime.h>
#include <math.h>

#define S_LEN 2048
#define NH 16
#define DH 128
#define INNER 2048   // NH*DH
#define NROWS 4096   // B*S

typedef __attribute__((ext_vector_type(8))) short bf16x8;
typedef __attribute__((ext_vector_type(4))) float f32x4;

__device__ __forceinline__ short f2bf(float f) {
  union { float f; unsigned u; } v; v.f = f;
  unsigned r = (v.u + 0x7fffu + ((v.u >> 16) & 1u)) >> 16;
  return (short)(unsigned short)r;
}
__device__ __forceinline__ float bf2f(short s) {
  union { unsigned u; float f; } v; v.u = ((unsigned)(unsigned short)s) << 16;
  return v.f;
}

// ---------------- fused prep ----------------
// grid 2048: [0,512) rope table [i][s]; [512,1024) X fp32->bf16;
//            [1024,1792) Wq/Wk/Wv transpose; [1792,2048) Wo transpose
__global__ void k_prep(const float* __restrict__ X, const float* __restrict__ Wq,
                       const float* __restrict__ Wk, const float* __restrict__ Wv,
                       const float* __restrict__ Wo,
                       float* __restrict__ rcT, float* __restrict__ rsT,
                       short* __restrict__ Xbf, short* __restrict__ WT,
                       short* __restrict__ WoT) {
  const int bx = blockIdx.x, tid = threadIdx.x;
  if (bx < 512) {
    int idx = bx * 256 + tid;           // 64 * S_LEN entries, [i][s]
    int i = idx >> 11, s = idx & 2047;
    double invf = pow(10000.0, -(double)i / 64.0);
    float ang = (float)((double)s * invf);
    float sv, cv; sincosf(ang, &sv, &cv);
    rcT[idx] = cv; rsT[idx] = sv;
    return;
  }
  if (bx < 1024) {
    int idx = ((bx - 512) * 256 + tid) * 4;
    float4 xv = *(const float4*)&X[idx];
    short4 o; o.x = f2bf(xv.x); o.y = f2bf(xv.y); o.z = f2bf(xv.z); o.w = f2bf(xv.w);
    *(short4*)&Xbf[idx] = o;
    return;
  }
  __shared__ float tile[32][33];
  const float* src; short* dst; int R, C, c0, r0;
  if (bx < 1792) {
    int z = (bx - 1024) >> 8, t = (bx - 1024) & 255;
    src = (z == 0) ? Wq : ((z == 1) ? Wk : Wv);
    dst = WT + (size_t)z * INNER * 128; R = 128; C = INNER;
    c0 = (t & 63) * 32; r0 = (t >> 6) * 32;
  } else {
    int t = bx - 1792;
    src = Wo; dst = WoT; R = INNER; C = 128;
    c0 = (t & 3) * 32; r0 = (t >> 2) * 32;
  }
  int tx = tid & 31, ty = tid >> 5;     // 32 x 8
  #pragma unroll
  for (int dy = 0; dy < 32; dy += 8)
    tile[ty + dy][tx] = src[(size_t)(r0 + ty + dy) * C + c0 + tx];
  __syncthreads();
  #pragma unroll
  for (int dy = 0; dy < 32; dy += 8)
    dst[(size_t)(c0 + ty + dy) * R + r0 + tx] = f2bf(tile[tx][ty + dy]);
}

// ---------------- fused QKV projection + RoPE ----------------
// grid (16 n-tiles of 128, 32 m-tiles of 128) = 512 blocks = 2/CU.
// Q,K [bh][s][d]; V [bh][d][s] via LDS transpose + coalesced dwordx4 stores.
__global__ __launch_bounds__(256, 2) void k_qkv(
    const short* __restrict__ Xbf, const short* __restrict__ WT,
    const float* __restrict__ rcT, const float* __restrict__ rsT,
    short* __restrict__ Qg, short* __restrict__ Kg, short* __restrict__ Vg) {
  __shared__ __attribute__((aligned(16))) short As[128 * 136];
  __shared__ __attribute__((aligned(16))) short Bs[128 * 136];
  const int tid = threadIdx.x;
  const int n0 = blockIdx.x * 128, m0 = blockIdx.y * 128;
  for (int e = tid; e < 2048; e += 256)
    *(int4*)&As[(e >> 4) * 136 + (e & 15) * 8] =
        *(const int4*)&Xbf[(size_t)(m0 + (e >> 4)) * 128 + (e & 15) * 8];
  const int wid = tid >> 6, lane = tid & 63;
  const int l16 = lane & 15, quad = lane >> 4;
  const int wm = (wid & 1) * 64, wn = (wid >> 1) * 64;
  const float qscale = 0.08838834764831845f;   // 1/sqrt(128) folded into Q
  for (int z = 0; z < 3; ++z) {
    __syncthreads();   // As ready (z=0) / prior MFMA LDS reads done (z>0)
    const short* Wp = WT + (size_t)z * INNER * 128;
    for (int e = tid; e < 2048; e += 256)
      *(int4*)&Bs[(e >> 4) * 136 + (e & 15) * 8] =
          *(const int4*)&Wp[(size_t)(n0 + (e >> 4)) * 128 + (e & 15) * 8];
    __syncthreads();
    f32x4 acc[4][4] = {};
    #pragma unroll
    for (int ks = 0; ks < 4; ++ks) {
      bf16x8 a[4], b[4];
      #pragma unroll
      for (int mt = 0; mt < 4; ++mt)
        a[mt] = *(const bf16x8*)&As[(wm + mt * 16 + l16) * 136 + ks * 32 + quad * 8];
      #pragma unroll
      for (int nt = 0; nt < 4; ++nt)
        b[nt] = *(const bf16x8*)&Bs[(wn + nt * 16 + l16) * 136 + ks * 32 + quad * 8];
      #pragma unroll
      for (int mt = 0; mt < 4; ++mt)
        #pragma unroll
        for (int nt = 0; nt < 4; ++nt)
          acc[mt][nt] = __builtin_amdgcn_mfma_f32_16x16x32_bf16(a[mt], b[nt], acc[mt][nt], 0, 0, 0);
    }
    if (z < 2) {
      #pragma unroll
      for (int mt = 0; mt < 4; ++mt)
        #pragma unroll
        for (int nt = 0; nt < 4; ++nt) {
          int gn = n0 + wn + nt * 16 + l16;
          int h = gn >> 7, d = gn & 127, i = d >> 1;
          int gm0 = m0 + wm + mt * 16 + quad * 4;
          int bb = gm0 >> 11, s0 = gm0 & 2047;
          float4 c4 = *(const float4*)&rcT[i * S_LEN + s0];
          float4 s4 = *(const float4*)&rsT[i * S_LEN + s0];
          float cA[4] = {c4.x, c4.y, c4.z, c4.w};
          float sA[4] = {s4.x, s4.y, s4.z, s4.w};
          #pragma unroll
          for (int r = 0; r < 4; ++r) {
            float v = acc[mt][nt][r];
            float pv = __shfl_xor(v, 1);          // partner lane holds d^1
            float res = (d & 1) ? (v * cA[r] + pv * sA[r]) : (v * cA[r] - pv * sA[r]);
            if (z == 0) res *= qscale;
            size_t off = (((size_t)(bb * NH + h)) * S_LEN + s0 + r) * DH + d;
            short bv = f2bf(res);
            if (z == 0) Qg[off] = bv; else Kg[off] = bv;
          }
        }
    } else {
      // V: transpose through As (free now), then coalesced [bh][d][s] stores
      __syncthreads();          // all waves done reading As for z==2 MFMA
      #pragma unroll
      for (int mt = 0; mt < 4; ++mt)
        #pragma unroll
        for (int nt = 0; nt < 4; ++nt) {
          int dl = wn + nt * 16 + l16;           // 0..127
          int sl = wm + mt * 16 + quad * 4;      // 0..124
          short4 pk;
          pk.x = f2bf(acc[mt][nt][0]); pk.y = f2bf(acc[mt][nt][1]);
          pk.z = f2bf(acc[mt][nt][2]); pk.w = f2bf(acc[mt][nt][3]);
          *(short4*)&As[dl * 136 + sl] = pk;
        }
      __syncthreads();
      const int bb = m0 >> 11, ss0 = m0 & 2047;
      #pragma unroll
      for (int rd = 0; rd < 8; ++rd) {
        int dl = (tid >> 4) + rd * 16;           // 0..127
        int sl = (tid & 15) * 8;                 // lanes cover s contiguously
        int gn = n0 + dl, h = gn >> 7, dd = gn & 127;
        int4 vv = *(const int4*)&As[dl * 136 + sl];
        *(int4*)&Vg[(((size_t)(bb * NH + h)) * DH + dd) * S_LEN + ss0 + sl] = vv;
      }
    }
  }
}

// ---------------- flash attention: split-t balanced blocks ----------------
// 512 blocks (bh = bid&31 -> XCD=bh%8 L2 locality; unit = bid>>5).
// Each block: EXACTLY 17 iterations = segment(q-tile=unit, even t-tiles) +
// segment(q-tile=15-unit, odd t-tiles). Per segment: independent online
// softmax -> unnormalized O (bf16) + (m,l) to workspace; k_out merges.
// Equal-length blocks => 2 fully-overlapping blocks/CU for ANY dispatch map.
__global__ __launch_bounds__(256, 2) void k_attn(
    const short* __restrict__ Qg, const short* __restrict__ Kg,
    const short* __restrict__ Vg, short* __restrict__ Op,
    float* __restrict__ mlb) {
  __shared__ __attribute__((aligned(16))) short Ks[2][64 * 136];   // [t][d] dbuf
  __shared__ __attribute__((aligned(16))) short Vs[128 * 72];      // [d][t] single
  __shared__ __attribute__((aligned(16))) short Ps[4][32 * 72];    // per-wave [q][t]
  const int bid = blockIdx.x;
  const int bh = bid & 31, unit = bid >> 5;
  const int tid = threadIdx.x, wid = tid >> 6, lane = tid & 63;
  const int l16 = lane & 15, quad = lane >> 4, wq = wid * 32;
  const short* Qp = Qg + (size_t)bh * S_LEN * DH;   // [s][d]
  const short* Kp = Kg + (size_t)bh * S_LEN * DH;   // [s][d]
  const short* Vp = Vg + (size_t)bh * S_LEN * DH;   // [d][s]
  short* psw = &Ps[wid][0];
  int4 kr[4], vr[4];

  for (int seg = 0; seg < 2; ++seg) {
    const int qg = seg ? (15 - unit) : unit;
    const int par = seg;                 // t-tile parity this segment owns
    const int q0 = qg * 128, nj = qg + 1;
    // Q fragments -> registers
    bf16x8 qf[4][2];
    #pragma unroll
    for (int ks = 0; ks < 4; ++ks)
      #pragma unroll
      for (int qb = 0; qb < 2; ++qb)
        qf[ks][qb] = *(const bf16x8*)&Qp[(size_t)(q0 + wq + qb * 16 + l16) * DH +
                                         ks * 32 + quad * 8];
    // stage first tile (j = par)
    #pragma unroll
    for (int i = 0; i < 4; ++i) {
      int e = tid + 256 * i;
      kr[i] = *(const int4*)&Kp[(size_t)(par * 64 + (e >> 4)) * DH + (e & 15) * 8];
      vr[i] = *(const int4*)&Vp[(size_t)(e >> 3) * S_LEN + par * 64 + (e & 7) * 8];
    }
    #pragma unroll
    for (int i = 0; i < 4; ++i) {
      int e = tid + 256 * i;
      *(int4*)&Ks[0][(e >> 4) * 136 + (e & 15) * 8] = kr[i];
      *(int4*)&Vs[(e >> 3) * 72 + (e & 7) * 8] = vr[i];
    }
    float m_i[2] = {-1e30f, -1e30f}, l_i[2] = {0.0f, 0.0f};
    f32x4 Oacc[8][2] = {};
    __syncthreads();
    for (int jj = 0; jj < nj; ++jj) {
      const int j = par + 2 * jj;
      const int b = jj & 1;
      if (jj + 1 < nj) {   // register-prefetch tile j+2
        #pragma unroll
        for (int i = 0; i < 4; ++i) {
          int e = tid + 256 * i;
          kr[i] = *(const int4*)&Kp[(size_t)((j + 2) * 64 + (e >> 4)) * DH + (e & 15) * 8];
          vr[i] = *(const int4*)&Vp[(size_t)(e >> 3) * S_LEN + (j + 2) * 64 + (e & 7) * 8];
        }
      }
      // S^T = K @ Q^T : per wave t=64 x q=32
      f32x4 Sc[4][2] = {};
      #pragma unroll
      for (int ks = 0; ks < 4; ++ks) {
        bf16x8 kfr[4];
        #pragma unroll
        for (int nt = 0; nt < 4; ++nt)
          kfr[nt] = *(const bf16x8*)&Ks[b][(nt * 16 + l16) * 136 + ks * 32 + quad * 8];
        #pragma unroll
        for (int nt = 0; nt < 4; ++nt)
          #pragma unroll
          for (int qb = 0; qb < 2; ++qb)
            Sc[nt][qb] = __builtin_amdgcn_mfma_f32_16x16x32_bf16(kfr[nt], qf[ks][qb],
                                                                 Sc[nt][qb], 0, 0, 0);
      }
      if (jj == nj - 1) {   // only the last tile of each segment touches diagonal
        #pragma unroll
        for (int nt = 0; nt < 4; ++nt)
          #pragma unroll
          for (int qb = 0; qb < 2; ++qb)
            #pragma unroll
            for (int r = 0; r < 4; ++r) {
              int tg = j * 64 + nt * 16 + quad * 4 + r;
              int qgl = q0 + wq + qb * 16 + l16;
              if (tg > qgl) Sc[nt][qb][r] = -3e30f;   // < m_init: exp -> 0
            }
      }
      // online softmax over t, per q-halftile
      #pragma unroll
      for (int qb = 0; qb < 2; ++qb) {
        float mloc = -3e30f;
        #pragma unroll
        for (int nt = 0; nt < 4; ++nt)
          #pragma unroll
          for (int r = 0; r < 4; ++r) mloc = fmaxf(mloc, Sc[nt][qb][r]);
        mloc = fmaxf(mloc, __shfl_xor(mloc, 16));
        mloc = fmaxf(mloc, __shfl_xor(mloc, 32));
        float mnew = fmaxf(m_i[qb], mloc);
        float alpha = __expf(m_i[qb] - mnew);
        m_i[qb] = mnew;
        float rsum = 0.0f;
        #pragma unroll
        for (int nt = 0; nt < 4; ++nt)
          #pragma unroll
          for (int r = 0; r < 4; ++r) {
            float pe = __expf(Sc[nt][qb][r] - mnew);
            Sc[nt][qb][r] = pe;
            rsum += pe;
          }
        rsum += __shfl_xor(rsum, 16);
        rsum += __shfl_xor(rsum, 32);
        l_i[qb] = l_i[qb] * alpha + rsum;
        #pragma unroll
        for (int nt = 0; nt < 8; ++nt)
          #pragma unroll
          for (int r = 0; r < 4; ++r) Oacc[nt][qb][r] *= alpha;
        // P^T -> wave-private LDS slab (C-layout -> B-operand layout)
        #pragma unroll
        for (int nt = 0; nt < 4; ++nt) {
          short4 pk;
          pk.x = f2bf(Sc[nt][qb][0]); pk.y = f2bf(Sc[nt][qb][1]);
          pk.z = f2bf(Sc[nt][qb][2]); pk.w = f2bf(Sc[nt][qb][3]);
          *(short4*)&psw[(qb * 16 + l16) * 72 + nt * 16 + quad * 4] = pk;
        }
      }
      // O^T += V^T @ P
      #pragma unroll
      for (int ks = 0; ks < 2; ++ks) {
        bf16x8 vfr[8];
        #pragma unroll
        for (int nt = 0; nt < 8; ++nt)
          vfr[nt] = *(const bf16x8*)&Vs[(nt * 16 + l16) * 72 + ks * 32 + quad * 8];
        bf16x8 bp[2];
        #pragma unroll
        for (int qb = 0; qb < 2; ++qb)
          bp[qb] = *(const bf16x8*)&psw[(qb * 16 + l16) * 72 + ks * 32 + quad * 8];
        #pragma unroll
        for (int nt = 0; nt < 8; ++nt)
          #pragma unroll
          for (int qb = 0; qb < 2; ++qb)
            Oacc[nt][qb] = __builtin_amdgcn_mfma_f32_16x16x32_bf16(vfr[nt], bp[qb],
                                                                   Oacc[nt][qb], 0, 0, 0);
      }
      __syncthreads();    // all reads of Ks[b]/Vs complete
      if (jj + 1 < nj) {
        #pragma unroll
        for (int i = 0; i < 4; ++i) {
          int e = tid + 256 * i;
          *(int4*)&Ks[1 - b][(e >> 4) * 136 + (e & 15) * 8] = kr[i];
          *(int4*)&Vs[(e >> 3) * 72 + (e & 7) * 8] = vr[i];
        }
      }
      __syncthreads();    // staged writes visible
    }
    // write unnormalized O^T partial + (m, l); k_out merges parities
    #pragma unroll
    for (int qb = 0; qb < 2; ++qb) {
      int qrow = q0 + wq + qb * 16 + l16;
      size_t orow = ((size_t)(par * 32 + bh) * S_LEN + qrow) * DH;
      #pragma unroll
      for (int nt = 0; nt < 8; ++nt) {
        short4 ov;
        ov.x = f2bf(Oacc[nt][qb][0]); ov.y = f2bf(Oacc[nt][qb][1]);
        ov.z = f2bf(Oacc[nt][qb][2]); ov.w = f2bf(Oacc[nt][qb][3]);
        *(short4*)&Op[orow + nt * 16 + quad * 4] = ov;
      }
      if (quad == 0)
        *(float2*)&mlb[((size_t)(par * 32 + bh) * S_LEN + qrow) * 2] =
            make_float2(m_i[qb], l_i[qb]);
    }
  }
}

// ---------------- output projection with parity merge ----------------
// grid (64 m-tiles of 64, splitK 4) = 256 blocks; atomicAdd into zeroed out.
// A-staging merges Op parity halves: merged = c1*O1 + c2*O2 with per-(row,h)
// weights c_i = e^{m_i-m} / (w1*l1 + w2*l2) precomputed in LDS.
__global__ __launch_bounds__(256) void k_out(
    const short* __restrict__ Op, const float* __restrict__ mlb,
    const short* __restrict__ WoT, float* __restrict__ out) {
  __shared__ __attribute__((aligned(16))) short As[64 * 72];
  __shared__ __attribute__((aligned(16))) short Bs[128 * 72];
  __shared__ float cw[4][64][2];
  const int m0 = blockIdx.x * 64, kb0 = blockIdx.y * 512;
  const int tid = threadIdx.x, wid = tid >> 6, lane = tid & 63;
  const int l16 = lane & 15, quad = lane >> 4;
  const int wm = (wid & 1) * 32, wn = (wid >> 1) * 64;
  {
    int rr = tid & 63, hh = tid >> 6;
    int row = m0 + rr, b = row >> 11, s = row & 2047;
    int bh = b * NH + (kb0 >> 7) + hh;
    float2 a1 = *(const float2*)&mlb[((size_t)bh * S_LEN + s) * 2];
    float2 a2 = *(const float2*)&mlb[((size_t)(32 + bh) * S_LEN + s) * 2];
    float mm = fmaxf(a1.x, a2.x);
    float w1 = __expf(a1.x - mm), w2 = __expf(a2.x - mm);
    float inv = 1.0f / (w1 * a1.y + w2 * a2.y);
    cw[hh][rr][0] = w1 * inv; cw[hh][rr][1] = w2 * inv;
  }
  __syncthreads();
  f32x4 acc[2][4] = {};
  for (int kc = 0; kc < 8; ++kc) {
    int k0 = kb0 + kc * 64;
    int h = k0 >> 7, d0 = k0 & 127, hh = kc >> 1;
    #pragma unroll
    for (int it = 0; it < 4; ++it) {
      int e = tid + 256 * it;                  // 1024 short4-units = 64x64
      int rr = e >> 4, c4 = (e & 15) * 4;
      int row = m0 + rr, b = row >> 11, s = row & 2047;
      size_t base = ((size_t)(b * NH + h) * S_LEN + s) * DH + d0 + c4;
      short4 u1 = *(const short4*)&Op[base];
      short4 u2 = *(const short4*)&Op[(size_t)32 * S_LEN * DH + base];
      float c1 = cw[hh][rr][0], c2 = cw[hh][rr][1];
      short4 o;
      o.x = f2bf(c1 * bf2f(u1.x) + c2 * bf2f(u2.x));
      o.y = f2bf(c1 * bf2f(u1.y) + c2 * bf2f(u2.y));
      o.z = f2bf(c1 * bf2f(u1.z) + c2 * bf2f(u2.z));
      o.w = f2bf(c1 * bf2f(u1.w) + c2 * bf2f(u2.w));
      *(short4*)&As[rr * 72 + c4] = o;
    }
    for (int e = tid; e < 1024; e += 256)
      *(int4*)&Bs[(e >> 3) * 72 + (e & 7) * 8] =
          *(const int4*)&WoT[(size_t)(e >> 3) * INNER + k0 + (e & 7) * 8];
    __syncthreads();
    #pragma unroll
    for (int ks = 0; ks < 2; ++ks) {
      bf16x8 a[2], b[4];
      #pragma unroll
      for (int mt = 0; mt < 2; ++mt)
        a[mt] = *(const bf16x8*)&As[(wm + mt * 16 + l16) * 72 + ks * 32 + quad * 8];
      #pragma unroll
      for (int nt = 0; nt < 4; ++nt)
        b[nt] = *(const bf16x8*)&Bs[(wn + nt * 16 + l16) * 72 + ks * 32 + quad * 8];
      #pragma unroll
      for (int mt = 0; mt < 2; ++mt)
        #pragma unroll
        for (int nt = 0; nt < 4; ++nt)
          acc[mt][nt] = __builtin_amdgcn_mfma_f32_16x16x32_bf16(a[mt], b[nt], acc[mt][nt], 0, 0, 0);
    }
    __syncthreads();
  }
  #pragma unroll
  for (int mt = 0; mt < 2; ++mt)
    #pragma unroll
    for (int nt = 0; nt < 4; ++nt)
      #pragma unroll
      for (int r = 0; r < 4; ++r) {
        int gm = m0 + wm + mt * 16 + quad * 4 + r;
        int gn = wn + nt * 16 + l16;
        atomicAdd(&out[(size_t)gm * 128 + gn], acc[mt][nt][r]);
      }
}

// ---------------- launch ----------------
extern "C" void kernel_launch(void* const* d_in, const int* in_sizes, int n_in,
                              void* d_out, int out_size, void* d_ws, size_t ws_size,
                              hipStream_t stream) {
  const float* q  = (const float*)d_in[0];
  const float* Wq = (const float*)d_in[1];
  const float* Wk = (const float*)d_in[2];
  const float* Wv = (const float*)d_in[3];
  const float* Wo = (const float*)d_in[4];
  float* out = (float*)d_out;
  char* ws = (char*)d_ws;
  const size_t MB = 1024 * 1024;
  float* rcT = (float*)(ws + 0);                   // 512 KB  [i][s]
  float* rsT = (float*)(ws + 512 * 1024);          // 512 KB  [i][s]
  short* WT  = (short*)(ws + 1 * MB);              // 1.5 MB (Wq,Wk,Wv [n][k] bf16)
  short* WoT = (short*)(ws + 2 * MB + 512 * 1024); // 512 KB
  short* Xbf = (short*)(ws + 3 * MB);              // 2 MB   [b*s][e] bf16
  short* Qg  = (short*)(ws + 8 * MB);              // 16 MB  [bh][s][d]
  short* Kg  = (short*)(ws + 24 * MB);             // 16 MB  [bh][s][d]
  short* Vg  = (short*)(ws + 40 * MB);             // 16 MB  [bh][d][s]
  short* Op  = (short*)(ws + 56 * MB);             // 32 MB  [par][bh][s][d] unnorm
  float* mlb = (float*)(ws + 88 * MB);             // 1 MB   [par][bh][s]{m,l}

  k_prep<<<2048, 256, 0, stream>>>(q, Wq, Wk, Wv, Wo, rcT, rsT, Xbf, WT, WoT);
  k_qkv<<<dim3(16, 32), 256, 0, stream>>>(Xbf, WT, rcT, rsT, Qg, Kg, Vg);
  k_attn<<<512, 256, 0, stream>>>(Qg, Kg, Vg, Op, mlb);
  hipMemsetAsync(d_out, 0, (size_t)out_size * sizeof(float), stream);
  k_out<<<dim3(64, 4), 256, 0, stream>>>(Op, mlb, WoT, out);
}

// Round 7
// 220.270 us; speedup vs baseline: 1.8817x; 1.0418x over previous
//
#include <hip/hip_runtime.h>
#include <math.h>

#define S_LEN 2048
#define NH 16
#define DH 128
#define INNER 2048   // NH*DH
#define NROWS 4096   // B*S

typedef __attribute__((ext_vector_type(8))) short bf16x8;
typedef __attribute__((ext_vector_type(4))) float f32x4;

__device__ __forceinline__ short f2bf(float f) {
  union { float f; unsigned u; } v; v.f = f;
  unsigned r = (v.u + 0x7fffu + ((v.u >> 16) & 1u)) >> 16;
  return (short)(unsigned short)r;
}
__device__ __forceinline__ float bf2f(short s) {
  union { unsigned u; float f; } v; v.u = ((unsigned)(unsigned short)s) << 16;
  return v.f;
}

// ---------------- fused prep ----------------
// grid 2048: [0,512) rope table [i][s]; [512,1024) X fp32->bf16;
//            [1024,1792) Wq/Wk/Wv transpose; [1792,2048) Wo transpose
__global__ void k_prep(const float* __restrict__ X, const float* __restrict__ Wq,
                       const float* __restrict__ Wk, const float* __restrict__ Wv,
                       const float* __restrict__ Wo,
                       float* __restrict__ rcT, float* __restrict__ rsT,
                       short* __restrict__ Xbf, short* __restrict__ WT,
                       short* __restrict__ WoT) {
  const int bx = blockIdx.x, tid = threadIdx.x;
  if (bx < 512) {
    int idx = bx * 256 + tid;           // 64 * S_LEN entries, [i][s]
    int i = idx >> 11, s = idx & 2047;
    double invf = pow(10000.0, -(double)i / 64.0);
    float ang = (float)((double)s * invf);
    float sv, cv; sincosf(ang, &sv, &cv);
    rcT[idx] = cv; rsT[idx] = sv;
    return;
  }
  if (bx < 1024) {
    int idx = ((bx - 512) * 256 + tid) * 4;
    float4 xv = *(const float4*)&X[idx];
    short4 o; o.x = f2bf(xv.x); o.y = f2bf(xv.y); o.z = f2bf(xv.z); o.w = f2bf(xv.w);
    *(short4*)&Xbf[idx] = o;
    return;
  }
  __shared__ float tile[32][33];
  const float* src; short* dst; int R, C, c0, r0;
  if (bx < 1792) {
    int z = (bx - 1024) >> 8, t = (bx - 1024) & 255;
    src = (z == 0) ? Wq : ((z == 1) ? Wk : Wv);
    dst = WT + (size_t)z * INNER * 128; R = 128; C = INNER;
    c0 = (t & 63) * 32; r0 = (t >> 6) * 32;
  } else {
    int t = bx - 1792;
    src = Wo; dst = WoT; R = INNER; C = 128;
    c0 = (t & 3) * 32; r0 = (t >> 2) * 32;
  }
  int tx = tid & 31, ty = tid >> 5;     // 32 x 8
  #pragma unroll
  for (int dy = 0; dy < 32; dy += 8)
    tile[ty + dy][tx] = src[(size_t)(r0 + ty + dy) * C + c0 + tx];
  __syncthreads();
  #pragma unroll
  for (int dy = 0; dy < 32; dy += 8)
    dst[(size_t)(c0 + ty + dy) * R + r0 + tx] = f2bf(tile[tx][ty + dy]);
}

// ---------------- fused QKV projection + RoPE ----------------
// grid (16 n-tiles of 128 = one head each, 32 m-tiles of 128) = 512 blocks.
// All epilogues route through LDS -> every global store instruction is
// 1KB-contiguous (R6 counters showed 8x HBM write amplification from
// strided per-lane stores). Q,K [bh][s][d]; V [bh][d][s].
__global__ __launch_bounds__(256, 2) void k_qkv(
    const short* __restrict__ Xbf, const short* __restrict__ WT,
    const float* __restrict__ rcT, const float* __restrict__ rsT,
    short* __restrict__ Qg, short* __restrict__ Kg, short* __restrict__ Vg) {
  __shared__ __attribute__((aligned(16))) short As[128 * 136];
  __shared__ __attribute__((aligned(16))) short Bs[128 * 136];
  const int tid = threadIdx.x;
  const int n0 = blockIdx.x * 128, m0 = blockIdx.y * 128;
  for (int e = tid; e < 2048; e += 256)
    *(int4*)&As[(e >> 4) * 136 + (e & 15) * 8] =
        *(const int4*)&Xbf[(size_t)(m0 + (e >> 4)) * 128 + (e & 15) * 8];
  const int wid = tid >> 6, lane = tid & 63;
  const int l16 = lane & 15, quad = lane >> 4;
  const int wm = (wid & 1) * 64, wn = (wid >> 1) * 64;
  const int hh = n0 >> 7;                       // this block's head
  const int bb = m0 >> 11, ss = m0 & 2047;      // batch, seq base
  const float qscale = 0.08838834764831845f;    // 1/sqrt(128) folded into Q
  for (int z = 0; z < 3; ++z) {
    __syncthreads();   // As/Bs ready for restage
    const short* Wp = WT + (size_t)z * INNER * 128;
    for (int e = tid; e < 2048; e += 256)
      *(int4*)&Bs[(e >> 4) * 136 + (e & 15) * 8] =
          *(const int4*)&Wp[(size_t)(n0 + (e >> 4)) * 128 + (e & 15) * 8];
    __syncthreads();
    f32x4 acc[4][4] = {};
    #pragma unroll
    for (int ks = 0; ks < 4; ++ks) {
      bf16x8 a[4], b[4];
      #pragma unroll
      for (int mt = 0; mt < 4; ++mt)
        a[mt] = *(const bf16x8*)&As[(wm + mt * 16 + l16) * 136 + ks * 32 + quad * 8];
      #pragma unroll
      for (int nt = 0; nt < 4; ++nt)
        b[nt] = *(const bf16x8*)&Bs[(wn + nt * 16 + l16) * 136 + ks * 32 + quad * 8];
      #pragma unroll
      for (int mt = 0; mt < 4; ++mt)
        #pragma unroll
        for (int nt = 0; nt < 4; ++nt)
          acc[mt][nt] = __builtin_amdgcn_mfma_f32_16x16x32_bf16(a[mt], b[nt], acc[mt][nt], 0, 0, 0);
    }
    if (z < 2) {
      // RoPE in regs, transpose-store through Bs (dead after MFMA), then
      // coalesced stores: block region = Q[bh][ss..ss+127][0..127] (32 KB).
      __syncthreads();                  // all waves done reading Bs
      #pragma unroll
      for (int mt = 0; mt < 4; ++mt)
        #pragma unroll
        for (int nt = 0; nt < 4; ++nt) {
          int d = wn + nt * 16 + l16, i = d >> 1;
          int sl0 = wm + mt * 16 + quad * 4;
          float4 c4 = *(const float4*)&rcT[i * S_LEN + ss + sl0];
          float4 s4 = *(const float4*)&rsT[i * S_LEN + ss + sl0];
          float cA[4] = {c4.x, c4.y, c4.z, c4.w};
          float sA[4] = {s4.x, s4.y, s4.z, s4.w};
          #pragma unroll
          for (int r = 0; r < 4; ++r) {
            float v = acc[mt][nt][r];
            float pv = __shfl_xor(v, 1);          // partner lane holds d^1
            float res = (d & 1) ? (v * cA[r] + pv * sA[r]) : (v * cA[r] - pv * sA[r]);
            if (z == 0) res *= qscale;
            Bs[(sl0 + r) * 136 + d] = f2bf(res);
          }
        }
      __syncthreads();
      short* dst = (z == 0 ? Qg : Kg) + (((size_t)(bb * NH + hh)) * S_LEN + ss) * DH;
      #pragma unroll
      for (int it = 0; it < 8; ++it) {
        int u = tid + 256 * it;                   // 2048 int4 units
        int row = u >> 4, col = (u & 15) * 8;
        *(int4*)&dst[(size_t)row * DH + col] = *(const int4*)&Bs[row * 136 + col];
      }
    } else {
      // V: transpose through As (dead now), coalesced [bh][d][s] stores
      __syncthreads();          // all waves done reading As
      #pragma unroll
      for (int mt = 0; mt < 4; ++mt)
        #pragma unroll
        for (int nt = 0; nt < 4; ++nt) {
          int dl = wn + nt * 16 + l16;           // 0..127
          int sl = wm + mt * 16 + quad * 4;      // 0..124
          short4 pk;
          pk.x = f2bf(acc[mt][nt][0]); pk.y = f2bf(acc[mt][nt][1]);
          pk.z = f2bf(acc[mt][nt][2]); pk.w = f2bf(acc[mt][nt][3]);
          *(short4*)&As[dl * 136 + sl] = pk;
        }
      __syncthreads();
      #pragma unroll
      for (int rd = 0; rd < 8; ++rd) {
        int dl = (tid >> 4) + rd * 16;           // 0..127
        int sl = (tid & 15) * 8;
        int4 vv = *(const int4*)&As[dl * 136 + sl];
        *(int4*)&Vg[(((size_t)(bb * NH + hh)) * DH + dl) * S_LEN + ss + sl] = vv;
      }
    }
  }
}

// ---------------- flash attention: split-t balanced blocks ----------------
// 512 blocks (bh = bid&31 -> XCD=bh%8 L2 locality; unit = bid>>5).
// Each block: EXACTLY 17 iterations = segment(q-tile=unit, even t-tiles) +
// segment(q-tile=15-unit, odd t-tiles). Per segment: independent online
// softmax -> unnormalized O (bf16) + (m,l) to workspace; k_out merges.
// O-epilogue routes through wave-private LDS (overlaid on dead Ks) so Op
// stores are 1KB-contiguous (fixes R6's 8x HBM write amplification).
__global__ __launch_bounds__(256, 2) void k_attn(
    const short* __restrict__ Qg, const short* __restrict__ Kg,
    const short* __restrict__ Vg, short* __restrict__ Op,
    float* __restrict__ mlb) {
  __shared__ __attribute__((aligned(16))) short Ks[2][64 * 136];   // [t][d] dbuf
  __shared__ __attribute__((aligned(16))) short Vs[128 * 72];      // [d][t] single
  __shared__ __attribute__((aligned(16))) short Ps[4][32 * 72];    // per-wave [q][t]
  const int bid = blockIdx.x;
  const int bh = bid & 31, unit = bid >> 5;
  const int tid = threadIdx.x, wid = tid >> 6, lane = tid & 63;
  const int l16 = lane & 15, quad = lane >> 4, wq = wid * 32;
  const short* Qp = Qg + (size_t)bh * S_LEN * DH;   // [s][d]
  const short* Kp = Kg + (size_t)bh * S_LEN * DH;   // [s][d]
  const short* Vp = Vg + (size_t)bh * S_LEN * DH;   // [d][s]
  short* psw = &Ps[wid][0];
  int4 kr[4], vr[4];

  for (int seg = 0; seg < 2; ++seg) {
    const int qg = seg ? (15 - unit) : unit;
    const int par = seg;                 // t-tile parity this segment owns
    const int q0 = qg * 128, nj = qg + 1;
    // Q fragments -> registers
    bf16x8 qf[4][2];
    #pragma unroll
    for (int ks = 0; ks < 4; ++ks)
      #pragma unroll
      for (int qb = 0; qb < 2; ++qb)
        qf[ks][qb] = *(const bf16x8*)&Qp[(size_t)(q0 + wq + qb * 16 + l16) * DH +
                                         ks * 32 + quad * 8];
    __syncthreads();   // protect Ks region reuse by prior segment's epilogue
    // stage first tile (j = par)
    #pragma unroll
    for (int i = 0; i < 4; ++i) {
      int e = tid + 256 * i;
      kr[i] = *(const int4*)&Kp[(size_t)(par * 64 + (e >> 4)) * DH + (e & 15) * 8];
      vr[i] = *(const int4*)&Vp[(size_t)(e >> 3) * S_LEN + par * 64 + (e & 7) * 8];
    }
    #pragma unroll
    for (int i = 0; i < 4; ++i) {
      int e = tid + 256 * i;
      *(int4*)&Ks[0][(e >> 4) * 136 + (e & 15) * 8] = kr[i];
      *(int4*)&Vs[(e >> 3) * 72 + (e & 7) * 8] = vr[i];
    }
    float m_i[2] = {-1e30f, -1e30f}, l_i[2] = {0.0f, 0.0f};
    f32x4 Oacc[8][2] = {};
    __syncthreads();
    for (int jj = 0; jj < nj; ++jj) {
      const int j = par + 2 * jj;
      const int b = jj & 1;
      if (jj + 1 < nj) {   // register-prefetch tile j+2
        #pragma unroll
        for (int i = 0; i < 4; ++i) {
          int e = tid + 256 * i;
          kr[i] = *(const int4*)&Kp[(size_t)((j + 2) * 64 + (e >> 4)) * DH + (e & 15) * 8];
          vr[i] = *(const int4*)&Vp[(size_t)(e >> 3) * S_LEN + (j + 2) * 64 + (e & 7) * 8];
        }
      }
      // S^T = K @ Q^T : per wave t=64 x q=32
      f32x4 Sc[4][2] = {};
      #pragma unroll
      for (int ks = 0; ks < 4; ++ks) {
        bf16x8 kfr[4];
        #pragma unroll
        for (int nt = 0; nt < 4; ++nt)
          kfr[nt] = *(const bf16x8*)&Ks[b][(nt * 16 + l16) * 136 + ks * 32 + quad * 8];
        #pragma unroll
        for (int nt = 0; nt < 4; ++nt)
          #pragma unroll
          for (int qb = 0; qb < 2; ++qb)
            Sc[nt][qb] = __builtin_amdgcn_mfma_f32_16x16x32_bf16(kfr[nt], qf[ks][qb],
                                                                 Sc[nt][qb], 0, 0, 0);
      }
      if (jj == nj - 1) {   // only the last tile of each segment touches diagonal
        #pragma unroll
        for (int nt = 0; nt < 4; ++nt)
          #pragma unroll
          for (int qb = 0; qb < 2; ++qb)
            #pragma unroll
            for (int r = 0; r < 4; ++r) {
              int tg = j * 64 + nt * 16 + quad * 4 + r;
              int qgl = q0 + wq + qb * 16 + l16;
              if (tg > qgl) Sc[nt][qb][r] = -3e30f;   // < m_init: exp -> 0
            }
      }
      // online softmax over t, per q-halftile
      #pragma unroll
      for (int qb = 0; qb < 2; ++qb) {
        float mloc = -3e30f;
        #pragma unroll
        for (int nt = 0; nt < 4; ++nt)
          #pragma unroll
          for (int r = 0; r < 4; ++r) mloc = fmaxf(mloc, Sc[nt][qb][r]);
        mloc = fmaxf(mloc, __shfl_xor(mloc, 16));
        mloc = fmaxf(mloc, __shfl_xor(mloc, 32));
        float mnew = fmaxf(m_i[qb], mloc);
        float alpha = __expf(m_i[qb] - mnew);
        m_i[qb] = mnew;
        float rsum = 0.0f;
        #pragma unroll
        for (int nt = 0; nt < 4; ++nt)
          #pragma unroll
          for (int r = 0; r < 4; ++r) {
            float pe = __expf(Sc[nt][qb][r] - mnew);
            Sc[nt][qb][r] = pe;
            rsum += pe;
          }
        rsum += __shfl_xor(rsum, 16);
        rsum += __shfl_xor(rsum, 32);
        l_i[qb] = l_i[qb] * alpha + rsum;
        #pragma unroll
        for (int nt = 0; nt < 8; ++nt)
          #pragma unroll
          for (int r = 0; r < 4; ++r) Oacc[nt][qb][r] *= alpha;
        // P^T -> wave-private LDS slab (C-layout -> B-operand layout)
        #pragma unroll
        for (int nt = 0; nt < 4; ++nt) {
          short4 pk;
          pk.x = f2bf(Sc[nt][qb][0]); pk.y = f2bf(Sc[nt][qb][1]);
          pk.z = f2bf(Sc[nt][qb][2]); pk.w = f2bf(Sc[nt][qb][3]);
          *(short4*)&psw[(qb * 16 + l16) * 72 + nt * 16 + quad * 4] = pk;
        }
      }
      // O^T += V^T @ P
      #pragma unroll
      for (int ks = 0; ks < 2; ++ks) {
        bf16x8 vfr[8];
        #pragma unroll
        for (int nt = 0; nt < 8; ++nt)
          vfr[nt] = *(const bf16x8*)&Vs[(nt * 16 + l16) * 72 + ks * 32 + quad * 8];
        bf16x8 bp[2];
        #pragma unroll
        for (int qb = 0; qb < 2; ++qb)
          bp[qb] = *(const bf16x8*)&psw[(qb * 16 + l16) * 72 + ks * 32 + quad * 8];
        #pragma unroll
        for (int nt = 0; nt < 8; ++nt)
          #pragma unroll
          for (int qb = 0; qb < 2; ++qb)
            Oacc[nt][qb] = __builtin_amdgcn_mfma_f32_16x16x32_bf16(vfr[nt], bp[qb],
                                                                   Oacc[nt][qb], 0, 0, 0);
      }
      __syncthreads();    // all reads of Ks[b]/Vs complete
      if (jj + 1 < nj) {
        #pragma unroll
        for (int i = 0; i < 4; ++i) {
          int e = tid + 256 * i;
          *(int4*)&Ks[1 - b][(e >> 4) * 136 + (e & 15) * 8] = kr[i];
          *(int4*)&Vs[(e >> 3) * 72 + (e & 7) * 8] = vr[i];
        }
      }
      __syncthreads();    // staged writes visible
    }
    // epilogue: unnormalized O^T -> wave-private slab on dead Ks, then
    // 1KB-contiguous global stores (in-wave DS ordering, no barrier needed)
    short* osl = ((short*)Ks) + wid * (32 * 136);
    #pragma unroll
    for (int qb = 0; qb < 2; ++qb)
      #pragma unroll
      for (int nt = 0; nt < 8; ++nt) {
        short4 ov;
        ov.x = f2bf(Oacc[nt][qb][0]); ov.y = f2bf(Oacc[nt][qb][1]);
        ov.z = f2bf(Oacc[nt][qb][2]); ov.w = f2bf(Oacc[nt][qb][3]);
        *(short4*)&osl[(qb * 16 + l16) * 136 + nt * 16 + quad * 4] = ov;
      }
    size_t obase = ((size_t)(par * 32 + bh) * S_LEN + q0 + wq) * DH;
    #pragma unroll
    for (int it = 0; it < 8; ++it) {
      int u = lane + 64 * it;                 // 512 int4 units = 32 rows x 16
      int row = u >> 4, col = (u & 15) * 8;
      *(int4*)&Op[obase + (size_t)row * DH + col] = *(const int4*)&osl[row * 136 + col];
    }
    #pragma unroll
    for (int qb = 0; qb < 2; ++qb) {
      int qrow = q0 + wq + qb * 16 + l16;
      if (quad == 0)
        *(float2*)&mlb[((size_t)(par * 32 + bh) * S_LEN + qrow) * 2] =
            make_float2(m_i[qb], l_i[qb]);
    }
  }
}

// ---------------- output projection with parity merge ----------------
// grid (64 m-tiles of 64, splitK 4) = 256 blocks; atomicAdd into zeroed out.
// A-staging merges Op parity halves: merged = c1*O1 + c2*O2 with per-(row,h)
// weights c_i = e^{m_i-m} / (w1*l1 + w2*l2) precomputed in LDS.
__global__ __launch_bounds__(256) void k_out(
    const short* __restrict__ Op, const float* __restrict__ mlb,
    const short* __restrict__ WoT, float* __restrict__ out) {
  __shared__ __attribute__((aligned(16))) short As[64 * 72];
  __shared__ __attribute__((aligned(16))) short Bs[128 * 72];
  __shared__ float cw[4][64][2];
  const int m0 = blockIdx.x * 64, kb0 = blockIdx.y * 512;
  const int tid = threadIdx.x, wid = tid >> 6, lane = tid & 63;
  const int l16 = lane & 15, quad = lane >> 4;
  const int wm = (wid & 1) * 32, wn = (wid >> 1) * 64;
  {
    int rr = tid & 63, hh = tid >> 6;
    int row = m0 + rr, b = row >> 11, s = row & 2047;
    int bh = b * NH + (kb0 >> 7) + hh;
    float2 a1 = *(const float2*)&mlb[((size_t)bh * S_LEN + s) * 2];
    float2 a2 = *(const float2*)&mlb[((size_t)(32 + bh) * S_LEN + s) * 2];
    float mm = fmaxf(a1.x, a2.x);
    float w1 = __expf(a1.x - mm), w2 = __expf(a2.x - mm);
    float inv = 1.0f / (w1 * a1.y + w2 * a2.y);
    cw[hh][rr][0] = w1 * inv; cw[hh][rr][1] = w2 * inv;
  }
  __syncthreads();
  f32x4 acc[2][4] = {};
  for (int kc = 0; kc < 8; ++kc) {
    int k0 = kb0 + kc * 64;
    int h = k0 >> 7, d0 = k0 & 127, hh = kc >> 1;
    #pragma unroll
    for (int it = 0; it < 4; ++it) {
      int e = tid + 256 * it;                  // 1024 short4-units = 64x64
      int rr = e >> 4, c4 = (e & 15) * 4;
      int row = m0 + rr, b = row >> 11, s = row & 2047;
      size_t base = ((size_t)(b * NH + h) * S_LEN + s) * DH + d0 + c4;
      short4 u1 = *(const short4*)&Op[base];
      short4 u2 = *(const short4*)&Op[(size_t)32 * S_LEN * DH + base];
      float c1 = cw[hh][rr][0], c2 = cw[hh][rr][1];
      short4 o;
      o.x = f2bf(c1 * bf2f(u1.x) + c2 * bf2f(u2.x));
      o.y = f2bf(c1 * bf2f(u1.y) + c2 * bf2f(u2.y));
      o.z = f2bf(c1 * bf2f(u1.z) + c2 * bf2f(u2.z));
      o.w = f2bf(c1 * bf2f(u1.w) + c2 * bf2f(u2.w));
      *(short4*)&As[rr * 72 + c4] = o;
    }
    for (int e = tid; e < 1024; e += 256)
      *(int4*)&Bs[(e >> 3) * 72 + (e & 7) * 8] =
          *(const int4*)&WoT[(size_t)(e >> 3) * INNER + k0 + (e & 7) * 8];
    __syncthreads();
    #pragma unroll
    for (int ks = 0; ks < 2; ++ks) {
      bf16x8 a[2], b[4];
      #pragma unroll
      for (int mt = 0; mt < 2; ++mt)
        a[mt] = *(const bf16x8*)&As[(wm + mt * 16 + l16) * 72 + ks * 32 + quad * 8];
      #pragma unroll
      for (int nt = 0; nt < 4; ++nt)
        b[nt] = *(const bf16x8*)&Bs[(wn + nt * 16 + l16) * 72 + ks * 32 + quad * 8];
      #pragma unroll
      for (int mt = 0; mt < 2; ++mt)
        #pragma unroll
        for (int nt = 0; nt < 4; ++nt)
          acc[mt][nt] = __builtin_amdgcn_mfma_f32_16x16x32_bf16(a[mt], b[nt], acc[mt][nt], 0, 0, 0);
    }
    __syncthreads();
  }
  #pragma unroll
  for (int mt = 0; mt < 2; ++mt)
    #pragma unroll
    for (int nt = 0; nt < 4; ++nt)
      #pragma unroll
      for (int r = 0; r < 4; ++r) {
        int gm = m0 + wm + mt * 16 + quad * 4 + r;
        int gn = wn + nt * 16 + l16;
        atomicAdd(&out[(size_t)gm * 128 + gn], acc[mt][nt][r]);
      }
}

// ---------------- launch ----------------
extern "C" void kernel_launch(void* const* d_in, const int* in_sizes, int n_in,
                              void* d_out, int out_size, void* d_ws, size_t ws_size,
                              hipStream_t stream) {
  const float* q  = (const float*)d_in[0];
  const float* Wq = (const float*)d_in[1];
  const float* Wk = (const float*)d_in[2];
  const float* Wv = (const float*)d_in[3];
  const float* Wo = (const float*)d_in[4];
  float* out = (float*)d_out;
  char* ws = (char*)d_ws;
  const size_t MB = 1024 * 1024;
  float* rcT = (float*)(ws + 0);                   // 512 KB  [i][s]
  float* rsT = (float*)(ws + 512 * 1024);          // 512 KB  [i][s]
  short* WT  = (short*)(ws + 1 * MB);              // 1.5 MB (Wq,Wk,Wv [n][k] bf16)
  short* WoT = (short*)(ws + 2 * MB + 512 * 1024); // 512 KB
  short* Xbf = (short*)(ws + 3 * MB);              // 2 MB   [b*s][e] bf16
  short* Qg  = (short*)(ws + 8 * MB);              // 16 MB  [bh][s][d]
  short* Kg  = (short*)(ws + 24 * MB);             // 16 MB  [bh][s][d]
  short* Vg  = (short*)(ws + 40 * MB);             // 16 MB  [bh][d][s]
  short* Op  = (short*)(ws + 56 * MB);             // 32 MB  [par][bh][s][d] unnorm
  float* mlb = (float*)(ws + 88 * MB);             // 1 MB   [par][bh][s]{m,l}

  k_prep<<<2048, 256, 0, stream>>>(q, Wq, Wk, Wv, Wo, rcT, rsT, Xbf, WT, WoT);
  k_qkv<<<dim3(16, 32), 256, 0, stream>>>(Xbf, WT, rcT, rsT, Qg, Kg, Vg);
  k_attn<<<512, 256, 0, stream>>>(Qg, Kg, Vg, Op, mlb);
  hipMemsetAsync(d_out, 0, (size_t)out_size * sizeof(float), stream);
  k_out<<<dim3(64, 4), 256, 0, stream>>>(Op, mlb, WoT, out);
}